// Round 1
// baseline (926.839 us; speedup 1.0000x reference)
//
#include <hip/hip_runtime.h>
#include <math.h>

#define NB 8
#define HH 128
#define WW 128
#define CIN 256
#define CH 128
#define CC2 256
#define WF1 65
#define HQ 64
#define WQ 64
#define WFQ 33

static __device__ __forceinline__ int brev7(int x){ return (int)(__brev((unsigned)x) >> 25); }
static __device__ __forceinline__ int brev6(int x){ return (int)(__brev((unsigned)x) >> 26); }

// Radix-2 DIT stages on bit-reversed input in LDS. CSrow = &CS[r][0].
// sign = -1 forward (matches numpy rfft), +1 inverse.
template<int LOG2L, int NBF>
static __device__ __forceinline__ void fft_stages(float (*CSrow)[2], int l, float sign) {
  for (int st = 1; st <= LOG2L; st++) {
    int half = 1 << (st - 1);
    float invm = 1.0f / (float)(1 << st);
    #pragma unroll
    for (int bi = 0; bi < NBF; bi++) {
      int b_ = l + 16 * bi;
      int pos = b_ & (half - 1);
      int i0 = ((b_ >> (st - 1)) << st) + pos;
      int i1 = i0 + half;
      float ang = sign * 6.283185307179586f * (float)pos * invm;
      float sn, cn; __sincosf(ang, &sn, &cn);
      float xr = CSrow[i1][0], xi = CSrow[i1][1];
      float tr = cn * xr - sn * xi, ti = cn * xi + sn * xr;
      float ur = CSrow[i0][0], ui = CSrow[i0][1];
      CSrow[i0][0] = ur + tr; CSrow[i0][1] = ui + ti;
      CSrow[i1][0] = ur - tr; CSrow[i1][1] = ui - ti;
    }
    __syncthreads();
  }
}

#define DOT16(WK, BASEPTR) do { \
  const float4* _ar = (const float4*)(BASEPTR); \
  float4 _a0 = _ar[0], _a1 = _ar[1], _a2 = _ar[2], _a3 = _ar[3]; \
  float _w = (WK); \
  acc[0]+=_w*_a0.x;  acc[1]+=_w*_a0.y;  acc[2]+=_w*_a0.z;  acc[3]+=_w*_a0.w; \
  acc[4]+=_w*_a1.x;  acc[5]+=_w*_a1.y;  acc[6]+=_w*_a1.z;  acc[7]+=_w*_a1.w; \
  acc[8]+=_w*_a2.x;  acc[9]+=_w*_a2.y;  acc[10]+=_w*_a2.z; acc[11]+=_w*_a2.w; \
  acc[12]+=_w*_a3.x; acc[13]+=_w*_a3.y; acc[14]+=_w*_a3.z; acc[15]+=_w*_a3.w; \
} while (0)

// ---------------- weight pre-transpose: WT4[k/4][co][4] = w[co][k] ----------------
__global__ void k_wt(const float* __restrict__ fu_w, const float* __restrict__ lfu_w,
                     const float* __restrict__ w2,
                     float4* __restrict__ fuT, float4* __restrict__ lfuT,
                     float4* __restrict__ w2T) {
  int t = blockIdx.x * 256 + threadIdx.x;
  if (t < 64 * 256) {
    int kq = t >> 8, co = t & 255;
    fuT[t]  = *(const float4*)&fu_w [co * 256 + 4 * kq];
    lfuT[t] = *(const float4*)&lfu_w[co * 256 + 4 * kq];
  }
  if (t < 32 * 256) {
    int cq = t >> 8, co = t & 255;
    w2T[t] = *(const float4*)&w2[co * 128 + 4 * cq];
  }
}

// ---------------- conv1 (NHWC x, K=256 -> 128) + BN + ReLU -> X1[n][h][c][w] -------
__global__ __launch_bounds__(256) void k_conv1(
    const float* __restrict__ x, const float* __restrict__ w1,
    const float* __restrict__ g1, const float* __restrict__ b1,
    const float* __restrict__ m1, const float* __restrict__ v1,
    float* __restrict__ X1) {
  __shared__ __align__(16) float AL[128][68];
  __shared__ __align__(16) float BL[128][68];
  int n = blockIdx.x / HH, h = blockIdx.x % HH;
  int t = threadIdx.x;
  const float* xrow = x + (size_t)(n * HH + h) * (WW * CIN);  // [w][cin]
  float acc[8][8];
  #pragma unroll
  for (int i = 0; i < 8; i++)
    #pragma unroll
    for (int j = 0; j < 8; j++) acc[i][j] = 0.0f;
  int wl = t & 15, cg = t >> 4;
  for (int kc = 0; kc < 4; kc++) {
    int k0 = kc * 64;
    #pragma unroll
    for (int p = 0; p < 8; p++) {
      int s = t + 256 * p; int row = s >> 4, q = s & 15;
      *(float4*)&AL[row][4 * q] = *(const float4*)&xrow[row * CIN + k0 + 4 * q];
      *(float4*)&BL[row][4 * q] = *(const float4*)&w1  [row * CIN + k0 + 4 * q];
    }
    __syncthreads();
    for (int kq = 0; kq < 16; kq++) {
      float4 a4[8], b4[8];
      #pragma unroll
      for (int i = 0; i < 8; i++) a4[i] = *(const float4*)&AL[wl + 16 * i][4 * kq];
      #pragma unroll
      for (int j = 0; j < 8; j++) b4[j] = *(const float4*)&BL[cg + 16 * j][4 * kq];
      #pragma unroll
      for (int i = 0; i < 8; i++)
        #pragma unroll
        for (int j = 0; j < 8; j++)
          acc[i][j] += a4[i].x * b4[j].x + a4[i].y * b4[j].y
                     + a4[i].z * b4[j].z + a4[i].w * b4[j].w;
    }
    __syncthreads();
  }
  float* orow = X1 + (size_t)(n * HH + h) * (CH * WW);  // [c][w]
  #pragma unroll
  for (int j = 0; j < 8; j++) {
    int co = cg + 16 * j;
    float sc = g1[co] * rsqrtf(v1[co] + 1e-3f);
    float sh = b1[co] - m1[co] * sc;
    #pragma unroll
    for (int i = 0; i < 8; i++) {
      int w = wl + 16 * i;
      float vv = acc[i][j] * sc + sh;
      orow[co * WW + w] = vv > 0.0f ? vv : 0.0f;
    }
  }
}

// ---------------- local Fourier unit: per (n,h2) row of the quadrant tensor --------
__global__ __launch_bounds__(256) void k_lfu(
    const float* __restrict__ X1, const float4* __restrict__ lfuT,
    const float* __restrict__ lg, const float* __restrict__ lb,
    const float* __restrict__ lm, const float* __restrict__ lv,
    float* __restrict__ XSO) {
  __shared__ __align__(16) float XA[128][64];
  __shared__ __align__(16) float FBl[257][36];
  __shared__ __align__(16) float CS[16][64][2];
  int n = blockIdx.x / HQ, h2 = blockIdx.x % HQ;
  int t = threadIdx.x;
  int r = t >> 4, l = t & 15;
  // load xs row: xs channel c2 = wb*64 + hb*32 + c0
  #pragma unroll
  for (int p = 0; p < 8; p++) {
    int s = t + 256 * p; int c2 = s >> 4, q = s & 15;
    int c0 = c2 & 31, hb = (c2 >> 5) & 1, wb = (c2 >> 6) & 1;
    const float* src = X1 + ((size_t)(n * HH + hb * 64 + h2) * CH + c0) * WW + wb * 64;
    *(float4*)&XA[c2][4 * q] = *(const float4*)&src[4 * q];
  }
  const float SC = 0.125f;  // 1/sqrt(64), both directions
  // forward FFT (64-pt) of 128 channels, 16 rows/group
  for (int g8 = 0; g8 < 8; g8++) {
    int c = g8 * 16 + r;
    __syncthreads();
    #pragma unroll
    for (int bi = 0; bi < 2; bi++) {
      int b_ = l + 16 * bi;
      int rv = brev6(b_);
      CS[r][rv][0]     = XA[c][b_] * SC;      CS[r][rv][1]     = 0.0f;
      CS[r][rv + 1][0] = XA[c][b_ + 32] * SC; CS[r][rv + 1][1] = 0.0f;
    }
    __syncthreads();
    fft_stages<6, 2>(&CS[r][0], l, -1.0f);
    #pragma unroll
    for (int bi = 0; bi < 2; bi++) {
      int wf = l + 16 * bi;
      FBl[2 * c][wf]     = CS[r][wf][0];
      FBl[2 * c + 1][wf] = CS[r][wf][1];
    }
    if (l == 0) { FBl[2 * c][32] = CS[r][32][0]; FBl[2 * c + 1][32] = CS[r][32][1]; }
  }
  __syncthreads();
  // freq-domain 256x256 conv + BN + ReLU, in place (per-column transform)
  {
    int co = t;
    float sc = lg[co] * rsqrtf(lv[co] + 1e-3f);
    float sh = lb[co] - lm[co] * sc;
    for (int ch = 0; ch < 3; ch++) {
      int wf0 = ch * 16;
      float acc[16];
      #pragma unroll
      for (int j = 0; j < 16; j++) acc[j] = 0.0f;
      for (int kq = 0; kq < 64; kq++) {
        float4 bw = lfuT[kq * 256 + co];
        DOT16(bw.x, &FBl[4 * kq + 0][wf0]);
        DOT16(bw.y, &FBl[4 * kq + 1][wf0]);
        DOT16(bw.z, &FBl[4 * kq + 2][wf0]);
        DOT16(bw.w, &FBl[4 * kq + 3][wf0]);
      }
      __syncthreads();
      #pragma unroll
      for (int j = 0; j < 16; j++) {
        int wf = wf0 + j;
        if (wf < WFQ) { float y = acc[j] * sc + sh; FBl[co][wf] = y > 0.0f ? y : 0.0f; }
      }
      __syncthreads();
    }
  }
  // inverse FFT (64-pt), write XSO[n][c][h2][w]
  for (int g8 = 0; g8 < 8; g8++) {
    int c = g8 * 16 + r;
    __syncthreads();
    #pragma unroll
    for (int bi = 0; bi < 2; bi++) {
      int b_ = l + 16 * bi;
      int rv = brev6(b_);
      CS[r][rv][0] = FBl[2 * c][b_]; CS[r][rv][1] = FBl[2 * c + 1][b_];
      float re1, im1;
      if (b_ == 0) { re1 = FBl[2 * c][32];       im1 =  FBl[2 * c + 1][32]; }
      else         { re1 = FBl[2 * c][32 - b_];  im1 = -FBl[2 * c + 1][32 - b_]; }
      CS[r][rv + 1][0] = re1; CS[r][rv + 1][1] = im1;
    }
    __syncthreads();
    fft_stages<6, 2>(&CS[r][0], l, +1.0f);
    float* orow = XSO + ((size_t)(n * CH + c) * HQ + h2) * WQ;
    #pragma unroll
    for (int bi = 0; bi < 2; bi++) {
      int w_ = l + 16 * bi;
      orow[w_]      = CS[r][w_][0] * SC;
      orow[w_ + 32] = CS[r][w_ + 32][0] * SC;
    }
  }
}

// ---------- fused Fourier unit + accumulate + final conv2, one block per (n,h) -----
__global__ __launch_bounds__(256) void k_fu(
    const float* __restrict__ X1, const float4* __restrict__ fuT,
    const float* __restrict__ fg, const float* __restrict__ fb,
    const float* __restrict__ fm, const float* __restrict__ fv,
    const float* __restrict__ XSO, const float4* __restrict__ w2T,
    float* __restrict__ out) {
  __shared__ __align__(16) float XA[CH][WW];     // 64 KB: x row, later acc row
  __shared__ __align__(16) float FBl[257][68];   // ~68 KB: ff, then y (in place)
  __shared__ __align__(16) float CS[16][WW][2];  // 16 KB FFT scratch
  int n = blockIdx.x / HH, h = blockIdx.x % HH;
  int t = threadIdx.x;
  int r = t >> 4, l = t & 15;
  {
    const float4* src = (const float4*)(X1 + (size_t)(n * HH + h) * CH * WW);
    float4* dst = (float4*)&XA[0][0];
    #pragma unroll
    for (int p = 0; p < 16; p++) dst[t + 256 * p] = src[t + 256 * p];
  }
  const float SC = 0.08838834764831845f;  // 1/sqrt(128), both directions
  // forward FFT (128-pt) of 128 channels
  for (int g8 = 0; g8 < 8; g8++) {
    int c = g8 * 16 + r;
    __syncthreads();
    #pragma unroll
    for (int bi = 0; bi < 4; bi++) {
      int b_ = l + 16 * bi;
      int rv = brev7(b_);
      CS[r][rv][0]     = XA[c][b_] * SC;      CS[r][rv][1]     = 0.0f;
      CS[r][rv + 1][0] = XA[c][b_ + 64] * SC; CS[r][rv + 1][1] = 0.0f;
    }
    __syncthreads();
    fft_stages<7, 4>(&CS[r][0], l, -1.0f);
    #pragma unroll
    for (int bi = 0; bi < 4; bi++) {
      int wf = l + 16 * bi;
      FBl[2 * c][wf]     = CS[r][wf][0];
      FBl[2 * c + 1][wf] = CS[r][wf][1];
    }
    if (l == 0) { FBl[2 * c][64] = CS[r][64][0]; FBl[2 * c + 1][64] = CS[r][64][1]; }
  }
  __syncthreads();
  // freq conv 256->256 + BN + ReLU, in place
  {
    int co = t;
    float sc = fg[co] * rsqrtf(fv[co] + 1e-3f);
    float sh = fb[co] - fm[co] * sc;
    for (int ch = 0; ch < 5; ch++) {
      int wf0 = ch * 16;
      float acc[16];
      #pragma unroll
      for (int j = 0; j < 16; j++) acc[j] = 0.0f;
      for (int kq = 0; kq < 64; kq++) {
        float4 bw = fuT[kq * 256 + co];
        DOT16(bw.x, &FBl[4 * kq + 0][wf0]);
        DOT16(bw.y, &FBl[4 * kq + 1][wf0]);
        DOT16(bw.z, &FBl[4 * kq + 2][wf0]);
        DOT16(bw.w, &FBl[4 * kq + 3][wf0]);
      }
      __syncthreads();
      #pragma unroll
      for (int j = 0; j < 16; j++) {
        int wf = wf0 + j;
        if (wf < WF1) { float y = acc[j] * sc + sh; FBl[co][wf] = y > 0.0f ? y : 0.0f; }
      }
      __syncthreads();
    }
  }
  // inverse FFT (128-pt); acc row: XA = x + irfft(y)*sqrt(W) + tiled lfu out
  for (int g8 = 0; g8 < 8; g8++) {
    int c = g8 * 16 + r;
    __syncthreads();
    #pragma unroll
    for (int bi = 0; bi < 4; bi++) {
      int b_ = l + 16 * bi;
      int rv = brev7(b_);
      CS[r][rv][0] = FBl[2 * c][b_]; CS[r][rv][1] = FBl[2 * c + 1][b_];
      float re1, im1;
      if (b_ == 0) { re1 = FBl[2 * c][64];       im1 =  FBl[2 * c + 1][64]; }
      else         { re1 = FBl[2 * c][64 - b_];  im1 = -FBl[2 * c + 1][64 - b_]; }
      CS[r][rv + 1][0] = re1; CS[r][rv + 1][1] = im1;
    }
    __syncthreads();
    fft_stages<7, 4>(&CS[r][0], l, +1.0f);
    const float* xsrow = XSO + ((size_t)(n * CH + c) * HQ + (h & 63)) * WQ;
    #pragma unroll
    for (int bi = 0; bi < 4; bi++) {
      int b_ = l + 16 * bi;
      float xv = xsrow[b_];
      XA[c][b_]      += CS[r][b_][0] * SC + xv;
      XA[c][b_ + 64] += CS[r][b_ + 64][0] * SC + xv;
    }
  }
  __syncthreads();
  // final conv2 (128 -> 256), write NHWC output
  {
    int co = t;
    float* obase = out + ((size_t)(n * HH + h) * WW) * CC2 + co;
    for (int ch = 0; ch < 8; ch++) {
      int w0 = ch * 16;
      float acc[16];
      #pragma unroll
      for (int j = 0; j < 16; j++) acc[j] = 0.0f;
      for (int cq = 0; cq < 32; cq++) {
        float4 bw = w2T[cq * 256 + co];
        DOT16(bw.x, &XA[4 * cq + 0][w0]);
        DOT16(bw.y, &XA[4 * cq + 1][w0]);
        DOT16(bw.z, &XA[4 * cq + 2][w0]);
        DOT16(bw.w, &XA[4 * cq + 3][w0]);
      }
      #pragma unroll
      for (int j = 0; j < 16; j++) obase[(size_t)(w0 + j) * CC2] = acc[j];
    }
  }
}

extern "C" void kernel_launch(void* const* d_in, const int* in_sizes, int n_in,
                              void* d_out, int out_size, void* d_ws, size_t ws_size,
                              hipStream_t stream) {
  const float* x     = (const float*)d_in[0];
  const float* w1    = (const float*)d_in[1];
  const float* g1    = (const float*)d_in[2];
  const float* b1    = (const float*)d_in[3];
  const float* m1    = (const float*)d_in[4];
  const float* v1    = (const float*)d_in[5];
  const float* fu_w  = (const float*)d_in[6];
  const float* fu_g  = (const float*)d_in[7];
  const float* fu_b  = (const float*)d_in[8];
  const float* fu_m  = (const float*)d_in[9];
  const float* fu_v  = (const float*)d_in[10];
  const float* lfu_w = (const float*)d_in[11];
  const float* lfu_g = (const float*)d_in[12];
  const float* lfu_b = (const float*)d_in[13];
  const float* lfu_m = (const float*)d_in[14];
  const float* lfu_v = (const float*)d_in[15];
  const float* w2    = (const float*)d_in[16];
  float* out = (float*)d_out;

  float* ws   = (float*)d_ws;
  float* X1   = ws;                          // 16,777,216 f (NHCW: [n][h][c][w])
  float* XSO  = X1 + 16777216;               // 4,194,304 f  ([n][c][h2][w2])
  float4* fuT  = (float4*)(XSO + 4194304);   // 16384 float4
  float4* lfuT = fuT + 16384;                // 16384 float4
  float4* w2T  = lfuT + 16384;               // 8192 float4

  hipLaunchKernelGGL(k_wt,    dim3(64),      dim3(256), 0, stream, fu_w, lfu_w, w2, fuT, lfuT, w2T);
  hipLaunchKernelGGL(k_conv1, dim3(NB * HH), dim3(256), 0, stream, x, w1, g1, b1, m1, v1, X1);
  hipLaunchKernelGGL(k_lfu,   dim3(NB * HQ), dim3(256), 0, stream, X1, lfuT, lfu_g, lfu_b, lfu_m, lfu_v, XSO);
  hipLaunchKernelGGL(k_fu,    dim3(NB * HH), dim3(256), 0, stream, X1, fuT, fu_g, fu_b, fu_m, fu_v, XSO, w2T, out);
}

// Round 2
// 436.471 us; speedup vs baseline: 2.1235x; 2.1235x over previous
//
#include <hip/hip_runtime.h>
#include <math.h>

#define NB 8
#define HH 128
#define WW 128
#define CIN 256
#define CH 128
#define WF1 65
#define HQ 64
#define WQ 64
#define WFQ 33
#define NCOL1 131072   /* n*h*w */
#define NCOLF 66560    /* n*h*65 */

typedef __attribute__((ext_vector_type(8))) short short8;
typedef __attribute__((ext_vector_type(4))) float f32x4;

static __device__ __forceinline__ int brev7(int x){ return (int)(__brev((unsigned)x) >> 25); }
static __device__ __forceinline__ int brev6(int x){ return (int)(__brev((unsigned)x) >> 26); }
static __device__ __forceinline__ unsigned short f2b(float f){
  unsigned u = __float_as_uint(f);
  u = (u + 0x7FFFu + ((u >> 16) & 1u)) >> 16;
  return (unsigned short)u;
}
static __device__ __forceinline__ float b2f(unsigned short u){
  return __uint_as_float(((unsigned)u) << 16);
}

// twiddle table: entry (half-1+pos) = exp(-i*pi*pos/half)
static __device__ __forceinline__ void tw_init(float (*TW)[2], int t, int n) {
  if (t < n) {
    int h_ = t + 1;
    int s = 31 - __clz(h_);
    int pos = h_ - (1 << s);
    float ang = -3.14159265358979323846f * (float)pos / (float)(1 << s);
    float sn, cn; sincosf(ang, &sn, &cn);
    TW[t][0] = cn; TW[t][1] = sn;
  }
}

// radix-2 DIT stages, bit-reversed input, table twiddles. INV=false: forward (rfft sign)
template<int LOG2L, int NBF, bool INV>
static __device__ __forceinline__ void fft_stages_tw(float (*CSrow)[2], const float (*TW)[2], int l) {
  for (int st = 1; st <= LOG2L; st++) {
    int half = 1 << (st - 1);
    #pragma unroll
    for (int bi = 0; bi < NBF; bi++) {
      int b_ = l + 16 * bi;
      int pos = b_ & (half - 1);
      int i0 = ((b_ >> (st - 1)) << st) + pos;
      int i1 = i0 + half;
      float cn = TW[half - 1 + pos][0];
      float sn = TW[half - 1 + pos][1];
      if (INV) sn = -sn;
      float xr = CSrow[i1][0], xi = CSrow[i1][1];
      float tr = cn * xr - sn * xi, ti = cn * xi + sn * xr;
      float ur = CSrow[i0][0], ui = CSrow[i0][1];
      CSrow[i0][0] = ur + tr; CSrow[i0][1] = ui + ti;
      CSrow[i1][0] = ur - tr; CSrow[i1][1] = ui - ti;
    }
    __syncthreads();
  }
}

#define DOT16(WK, BASEPTR) do { \
  const float4* _ar = (const float4*)(BASEPTR); \
  float4 _a0 = _ar[0], _a1 = _ar[1], _a2 = _ar[2], _a3 = _ar[3]; \
  float _w = (WK); \
  acc[0]+=_w*_a0.x;  acc[1]+=_w*_a0.y;  acc[2]+=_w*_a0.z;  acc[3]+=_w*_a0.w; \
  acc[4]+=_w*_a1.x;  acc[5]+=_w*_a1.y;  acc[6]+=_w*_a1.z;  acc[7]+=_w*_a1.w; \
  acc[8]+=_w*_a2.x;  acc[9]+=_w*_a2.y;  acc[10]+=_w*_a2.z; acc[11]+=_w*_a2.w; \
  acc[12]+=_w*_a3.x; acc[13]+=_w*_a3.y; acc[14]+=_w*_a3.z; acc[15]+=_w*_a3.w; \
} while (0)

// ---------------- weight prep: bf16 copies + BN scale/shift + lfu float4 pack ------
__global__ void k_wt(const float* __restrict__ w1, const float* __restrict__ fu_w,
                     const float* __restrict__ lfu_w, const float* __restrict__ w2,
                     const float* __restrict__ g1, const float* __restrict__ b1,
                     const float* __restrict__ m1, const float* __restrict__ v1,
                     const float* __restrict__ fg, const float* __restrict__ fb,
                     const float* __restrict__ fm, const float* __restrict__ fv,
                     unsigned short* __restrict__ w1b, unsigned short* __restrict__ fuwb,
                     unsigned short* __restrict__ w2b, float4* __restrict__ lfuT,
                     float* __restrict__ sc1, float* __restrict__ sh1,
                     float* __restrict__ scF, float* __restrict__ shF) {
  int t = blockIdx.x * 256 + threadIdx.x;
  if (t < 32768) { w1b[t] = f2b(w1[t]); w2b[t] = f2b(w2[t]); }
  if (t < 65536) fuwb[t] = f2b(fu_w[t]);
  if (t < 16384) {
    int kq = t >> 8, co = t & 255;
    lfuT[t] = *(const float4*)&lfu_w[co * 256 + 4 * kq];
  }
  if (t < 128) { float s = g1[t] * rsqrtf(v1[t] + 1e-3f); sc1[t] = s; sh1[t] = b1[t] - m1[t] * s; }
  if (t < 256) { float s = fg[t] * rsqrtf(fv[t] + 1e-3f); scF[t] = s; shF[t] = fb[t] - fm[t] * s; }
}

// ------------- generic MFMA GEMM: C^T[col][m] = (A[m][K] . B^T[col][K])^T ----------
// A bf16 row-major [MM][KK]; B^T rows = cols (bf16 or f32); optional BN+ReLU on m.
template<int MM, int KK, bool BF32, bool DOBN, bool OUTF32>
__global__ __launch_bounds__((MM / 64) * 128) void k_gemm(
    const unsigned short* __restrict__ A, const void* __restrict__ Bv,
    void* __restrict__ Cv, const float* __restrict__ scp, const float* __restrict__ shp) {
  int t = threadIdx.x;
  int wid = t >> 6, l = t & 63;
  int wm = wid >> 1, wn = wid & 1;
  int m0 = wm * 64;
  size_t n0 = (size_t)blockIdx.x * 128 + wn * 64;
  int lr = l & 15, lg = l >> 4;
  f32x4 acc[4][4];
  #pragma unroll
  for (int mt = 0; mt < 4; mt++)
    #pragma unroll
    for (int nt = 0; nt < 4; nt++) acc[mt][nt] = (f32x4){0.f, 0.f, 0.f, 0.f};
  #pragma unroll 2
  for (int kk = 0; kk < KK; kk += 32) {
    short8 af[4], bf[4];
    #pragma unroll
    for (int mt = 0; mt < 4; mt++)
      af[mt] = *(const short8*)(A + (size_t)(m0 + 16 * mt + lr) * KK + kk + lg * 8);
    if constexpr (BF32) {
      const float* Bf = (const float*)Bv;
      #pragma unroll
      for (int nt = 0; nt < 4; nt++) {
        const float* bp = Bf + (n0 + 16 * nt + lr) * KK + kk + lg * 8;
        float4 f0 = *(const float4*)bp, f1 = *(const float4*)(bp + 4);
        short8 bb;
        bb[0] = (short)f2b(f0.x); bb[1] = (short)f2b(f0.y);
        bb[2] = (short)f2b(f0.z); bb[3] = (short)f2b(f0.w);
        bb[4] = (short)f2b(f1.x); bb[5] = (short)f2b(f1.y);
        bb[6] = (short)f2b(f1.z); bb[7] = (short)f2b(f1.w);
        bf[nt] = bb;
      }
    } else {
      const unsigned short* Bb = (const unsigned short*)Bv;
      #pragma unroll
      for (int nt = 0; nt < 4; nt++)
        bf[nt] = *(const short8*)(Bb + (n0 + 16 * nt + lr) * KK + kk + lg * 8);
    }
    #pragma unroll
    for (int mt = 0; mt < 4; mt++)
      #pragma unroll
      for (int nt = 0; nt < 4; nt++)
        acc[mt][nt] = __builtin_amdgcn_mfma_f32_16x16x32_bf16(af[mt], bf[nt], acc[mt][nt], 0, 0, 0);
  }
  #pragma unroll
  for (int nt = 0; nt < 4; nt++) {
    size_t col = n0 + 16 * nt + lr;
    #pragma unroll
    for (int mt = 0; mt < 4; mt++) {
      int rb = m0 + 16 * mt + lg * 4;
      f32x4 v = acc[mt][nt];
      if constexpr (DOBN) {
        float4 s4 = *(const float4*)&scp[rb];
        float4 h4 = *(const float4*)&shp[rb];
        v[0] = fmaxf(v[0] * s4.x + h4.x, 0.f);
        v[1] = fmaxf(v[1] * s4.y + h4.y, 0.f);
        v[2] = fmaxf(v[2] * s4.z + h4.z, 0.f);
        v[3] = fmaxf(v[3] * s4.w + h4.w, 0.f);
      }
      if constexpr (OUTF32) {
        float4 o; o.x = v[0]; o.y = v[1]; o.z = v[2]; o.w = v[3];
        *(float4*)((float*)Cv + col * MM + rb) = o;
      } else {
        ushort4 u;
        u.x = f2b(v[0]); u.y = f2b(v[1]); u.z = f2b(v[2]); u.w = f2b(v[3]);
        *(ushort4*)((unsigned short*)Cv + col * MM + rb) = u;
      }
    }
  }
}

// ---------------- forward FFT: X1b[(nh w)][c] -> FFT[(nh*65+wf)][c2] bf16 ----------
__global__ __launch_bounds__(256) void k_fftf(const unsigned short* __restrict__ X1b,
                                              unsigned short* __restrict__ FFT) {
  __shared__ unsigned short XA[128][130];
  __shared__ float CS[16][129][2];
  __shared__ float TW[127][2];
  size_t nh = blockIdx.x;
  int t = threadIdx.x, r = t >> 4, l = t & 15;
  tw_init(TW, t, 127);
  {
    int w0 = t >> 4, q = t & 15;
    #pragma unroll
    for (int p = 0; p < 8; p++) {
      int w_ = w0 + 16 * p;
      uint4 dv = *(const uint4*)(X1b + (nh * 128 + w_) * 128 + 8 * q);
      int c0 = 8 * q;
      XA[c0+0][w_] = (unsigned short)(dv.x & 0xffffu); XA[c0+1][w_] = (unsigned short)(dv.x >> 16);
      XA[c0+2][w_] = (unsigned short)(dv.y & 0xffffu); XA[c0+3][w_] = (unsigned short)(dv.y >> 16);
      XA[c0+4][w_] = (unsigned short)(dv.z & 0xffffu); XA[c0+5][w_] = (unsigned short)(dv.z >> 16);
      XA[c0+6][w_] = (unsigned short)(dv.w & 0xffffu); XA[c0+7][w_] = (unsigned short)(dv.w >> 16);
    }
  }
  __syncthreads();
  const float SC = 0.08838834764831845f;  // 1/sqrt(128)
  for (int g8 = 0; g8 < 8; g8++) {
    int c = g8 * 16 + r;
    if (g8) __syncthreads();
    #pragma unroll
    for (int bi = 0; bi < 4; bi++) {
      int b_ = l + 16 * bi;
      int rv = brev7(b_);
      CS[r][rv][0]     = b2f(XA[c][b_]) * SC;      CS[r][rv][1]     = 0.0f;
      CS[r][rv + 1][0] = b2f(XA[c][b_ + 64]) * SC; CS[r][rv + 1][1] = 0.0f;
    }
    __syncthreads();
    fft_stages_tw<7, 4, false>(&CS[r][0], TW, l);
    #pragma unroll
    for (int p = 0; p < 5; p++) {
      int idx = t + 256 * p;
      if (idx < 1040) {
        int rr = idx & 15, wf = idx >> 4;
        unsigned pk = (unsigned)f2b(CS[rr][wf][0]) | ((unsigned)f2b(CS[rr][wf][1]) << 16);
        *(unsigned*)(FFT + (nh * 65 + wf) * 256 + 2 * (g8 * 16 + rr)) = pk;
      }
    }
  }
}

// ---- inverse FFT + residual accumulate: Yt + X1b + XSO -> ACC (in-place X1b) ------
__global__ __launch_bounds__(256) void k_ffti(const unsigned short* __restrict__ Yt,
                                              const float* __restrict__ XSO,
                                              unsigned short* __restrict__ X1b) {
  __shared__ unsigned short XA[128][130];
  __shared__ float CS[16][129][2];
  __shared__ float SB[65][33];
  __shared__ float TW[127][2];
  size_t nh = blockIdx.x;
  int n = blockIdx.x >> 7, h = blockIdx.x & 127;
  int t = threadIdx.x, r = t >> 4, l = t & 15;
  tw_init(TW, t, 127);
  {
    int w0 = t >> 4, q = t & 15;
    #pragma unroll
    for (int p = 0; p < 8; p++) {
      int w_ = w0 + 16 * p;
      uint4 dv = *(const uint4*)(X1b + (nh * 128 + w_) * 128 + 8 * q);
      int c0 = 8 * q;
      XA[c0+0][w_] = (unsigned short)(dv.x & 0xffffu); XA[c0+1][w_] = (unsigned short)(dv.x >> 16);
      XA[c0+2][w_] = (unsigned short)(dv.y & 0xffffu); XA[c0+3][w_] = (unsigned short)(dv.y >> 16);
      XA[c0+4][w_] = (unsigned short)(dv.z & 0xffffu); XA[c0+5][w_] = (unsigned short)(dv.z >> 16);
      XA[c0+6][w_] = (unsigned short)(dv.w & 0xffffu); XA[c0+7][w_] = (unsigned short)(dv.w >> 16);
    }
  }
  const float SC = 0.08838834764831845f;
  for (int g8 = 0; g8 < 8; g8++) {
    __syncthreads();
    #pragma unroll
    for (int p = 0; p < 9; p++) {
      int idx = t + 256 * p;
      if (idx < 2080) {
        int wf = idx >> 5, j = idx & 31;
        SB[wf][j] = b2f(Yt[(nh * 65 + wf) * 256 + g8 * 32 + j]);
      }
    }
    __syncthreads();
    int c = g8 * 16 + r;
    #pragma unroll
    for (int bi = 0; bi < 4; bi++) {
      int b_ = l + 16 * bi;
      int rv = brev7(b_);
      CS[r][rv][0] = SB[b_][2 * r];  CS[r][rv][1] = SB[b_][2 * r + 1];
      int mb = 64 - b_;
      CS[r][rv + 1][0] = SB[mb][2 * r];  CS[r][rv + 1][1] = -SB[mb][2 * r + 1];
    }
    __syncthreads();
    fft_stages_tw<7, 4, true>(&CS[r][0], TW, l);
    const float* xsrow = XSO + (((size_t)n * 128 + c) * 64 + (h & 63)) * 64;
    #pragma unroll
    for (int bi = 0; bi < 4; bi++) {
      int b_ = l + 16 * bi;
      float xv = xsrow[b_];
      float f0 = b2f(XA[c][b_]) + CS[r][b_][0] * SC + xv;
      float f1 = b2f(XA[c][b_ + 64]) + CS[r][b_ + 64][0] * SC + xv;
      XA[c][b_] = f2b(f0);
      XA[c][b_ + 64] = f2b(f1);
    }
  }
  __syncthreads();
  {
    int w0 = t >> 4, q = t & 15;
    #pragma unroll
    for (int p = 0; p < 8; p++) {
      int w_ = w0 + 16 * p;
      int c0 = 8 * q;
      uint4 dv;
      dv.x = (unsigned)XA[c0+0][w_] | ((unsigned)XA[c0+1][w_] << 16);
      dv.y = (unsigned)XA[c0+2][w_] | ((unsigned)XA[c0+3][w_] << 16);
      dv.z = (unsigned)XA[c0+4][w_] | ((unsigned)XA[c0+5][w_] << 16);
      dv.w = (unsigned)XA[c0+6][w_] | ((unsigned)XA[c0+7][w_] << 16);
      *(uint4*)(X1b + (nh * 128 + w_) * 128 + 8 * q) = dv;
    }
  }
}

// ---------------- local Fourier unit (fp32, input adapted to X1b layout) -----------
__global__ __launch_bounds__(256) void k_lfu(
    const unsigned short* __restrict__ X1b, const float4* __restrict__ lfuT,
    const float* __restrict__ lg_, const float* __restrict__ lb_,
    const float* __restrict__ lm_, const float* __restrict__ lv_,
    float* __restrict__ XSO) {
  __shared__ float XA[128][66];
  __shared__ float FBl[257][36];
  __shared__ float CS[16][64][2];
  __shared__ float TWl[63][2];
  int n = blockIdx.x / HQ, h2 = blockIdx.x % HQ;
  int t = threadIdx.x;
  int r = t >> 4, l = t & 15;
  tw_init(TWl, t, 63);
  #pragma unroll
  for (int ck = 0; ck < 4; ck++) {
    int hb = ck & 1, wb = ck >> 1;
    int w_ = t >> 2, q = t & 3;
    const unsigned short* src = X1b +
        ((size_t)((n * 128 + hb * 64 + h2)) * 128 + wb * 64 + w_) * 128 + 8 * q;
    uint4 dv = *(const uint4*)src;
    int c2 = wb * 64 + hb * 32 + 8 * q;
    XA[c2+0][w_] = b2f((unsigned short)(dv.x & 0xffffu)); XA[c2+1][w_] = b2f((unsigned short)(dv.x >> 16));
    XA[c2+2][w_] = b2f((unsigned short)(dv.y & 0xffffu)); XA[c2+3][w_] = b2f((unsigned short)(dv.y >> 16));
    XA[c2+4][w_] = b2f((unsigned short)(dv.z & 0xffffu)); XA[c2+5][w_] = b2f((unsigned short)(dv.z >> 16));
    XA[c2+6][w_] = b2f((unsigned short)(dv.w & 0xffffu)); XA[c2+7][w_] = b2f((unsigned short)(dv.w >> 16));
  }
  const float SC = 0.125f;  // 1/sqrt(64)
  for (int g8 = 0; g8 < 8; g8++) {
    int c = g8 * 16 + r;
    __syncthreads();
    #pragma unroll
    for (int bi = 0; bi < 2; bi++) {
      int b_ = l + 16 * bi;
      int rv = brev6(b_);
      CS[r][rv][0]     = XA[c][b_] * SC;      CS[r][rv][1]     = 0.0f;
      CS[r][rv + 1][0] = XA[c][b_ + 32] * SC; CS[r][rv + 1][1] = 0.0f;
    }
    __syncthreads();
    fft_stages_tw<6, 2, false>(&CS[r][0], TWl, l);
    #pragma unroll
    for (int bi = 0; bi < 2; bi++) {
      int wf = l + 16 * bi;
      FBl[2 * c][wf]     = CS[r][wf][0];
      FBl[2 * c + 1][wf] = CS[r][wf][1];
    }
    if (l == 0) { FBl[2 * c][32] = CS[r][32][0]; FBl[2 * c + 1][32] = CS[r][32][1]; }
  }
  __syncthreads();
  {
    int co = t;
    float sc = lg_[co] * rsqrtf(lv_[co] + 1e-3f);
    float sh = lb_[co] - lm_[co] * sc;
    for (int ch = 0; ch < 3; ch++) {
      int wf0 = ch * 16;
      float acc[16];
      #pragma unroll
      for (int j = 0; j < 16; j++) acc[j] = 0.0f;
      for (int kq = 0; kq < 64; kq++) {
        float4 bw = lfuT[kq * 256 + co];
        DOT16(bw.x, &FBl[4 * kq + 0][wf0]);
        DOT16(bw.y, &FBl[4 * kq + 1][wf0]);
        DOT16(bw.z, &FBl[4 * kq + 2][wf0]);
        DOT16(bw.w, &FBl[4 * kq + 3][wf0]);
      }
      __syncthreads();
      #pragma unroll
      for (int j = 0; j < 16; j++) {
        int wf = wf0 + j;
        if (wf < WFQ) { float y = acc[j] * sc + sh; FBl[co][wf] = y > 0.0f ? y : 0.0f; }
      }
      __syncthreads();
    }
  }
  for (int g8 = 0; g8 < 8; g8++) {
    int c = g8 * 16 + r;
    __syncthreads();
    #pragma unroll
    for (int bi = 0; bi < 2; bi++) {
      int b_ = l + 16 * bi;
      int rv = brev6(b_);
      CS[r][rv][0] = FBl[2 * c][b_]; CS[r][rv][1] = FBl[2 * c + 1][b_];
      float re1, im1;
      if (b_ == 0) { re1 = FBl[2 * c][32];       im1 =  FBl[2 * c + 1][32]; }
      else         { re1 = FBl[2 * c][32 - b_];  im1 = -FBl[2 * c + 1][32 - b_]; }
      CS[r][rv + 1][0] = re1; CS[r][rv + 1][1] = im1;
    }
    __syncthreads();
    fft_stages_tw<6, 2, true>(&CS[r][0], TWl, l);
    float* orow = XSO + ((size_t)(n * CH + c) * HQ + h2) * WQ;
    #pragma unroll
    for (int bi = 0; bi < 2; bi++) {
      int w_ = l + 16 * bi;
      orow[w_]      = CS[r][w_][0] * SC;
      orow[w_ + 32] = CS[r][w_ + 32][0] * SC;
    }
  }
}

extern "C" void kernel_launch(void* const* d_in, const int* in_sizes, int n_in,
                              void* d_out, int out_size, void* d_ws, size_t ws_size,
                              hipStream_t stream) {
  const float* x     = (const float*)d_in[0];
  const float* w1    = (const float*)d_in[1];
  const float* g1    = (const float*)d_in[2];
  const float* b1    = (const float*)d_in[3];
  const float* m1    = (const float*)d_in[4];
  const float* v1    = (const float*)d_in[5];
  const float* fu_w  = (const float*)d_in[6];
  const float* fu_g  = (const float*)d_in[7];
  const float* fu_b  = (const float*)d_in[8];
  const float* fu_m  = (const float*)d_in[9];
  const float* fu_v  = (const float*)d_in[10];
  const float* lfu_w = (const float*)d_in[11];
  const float* lfu_g = (const float*)d_in[12];
  const float* lfu_b = (const float*)d_in[13];
  const float* lfu_m = (const float*)d_in[14];
  const float* lfu_v = (const float*)d_in[15];
  const float* w2    = (const float*)d_in[16];
  float* out = (float*)d_out;

  char* p = (char*)d_ws;
  unsigned short* X1b  = (unsigned short*)p; p += (size_t)NCOL1 * 128 * 2;  // 32 MB (also ACC, in-place)
  unsigned short* FFT  = (unsigned short*)p; p += (size_t)NCOLF * 256 * 2;  // 32.5 MB
  unsigned short* Yt   = (unsigned short*)p; p += (size_t)NCOLF * 256 * 2;  // 32.5 MB
  float*          XSO  = (float*)p;          p += (size_t)4194304 * 4;      // 16 MB
  unsigned short* w1b  = (unsigned short*)p; p += 32768 * 2;
  unsigned short* fuwb = (unsigned short*)p; p += 65536 * 2;
  unsigned short* w2b  = (unsigned short*)p; p += 32768 * 2;
  float4*         lfuT = (float4*)p;         p += 16384 * 16;
  float* sc1 = (float*)p; p += 128 * 4;
  float* sh1 = (float*)p; p += 128 * 4;
  float* scF = (float*)p; p += 256 * 4;
  float* shF = (float*)p; p += 256 * 4;

  k_wt<<<dim3(256), dim3(256), 0, stream>>>(w1, fu_w, lfu_w, w2, g1, b1, m1, v1,
                                            fu_g, fu_b, fu_m, fu_v,
                                            w1b, fuwb, w2b, lfuT, sc1, sh1, scF, shF);
  // conv1: A=w1b[128][256], B^T=x[(nhw)][256] f32 -> X1b[(nhw)][128] bf16 (+BN+ReLU)
  k_gemm<128, 256, true, true, false><<<dim3(NCOL1 / 128), dim3(256), 0, stream>>>(
      w1b, (const void*)x, (void*)X1b, sc1, sh1);
  // local fourier unit (fp32) -> XSO
  k_lfu<<<dim3(NB * HQ), dim3(256), 0, stream>>>(X1b, lfuT, lfu_g, lfu_b, lfu_m, lfu_v, XSO);
  // forward FFT -> FFT[(nh*65+wf)][256]
  k_fftf<<<dim3(NB * HH), dim3(256), 0, stream>>>(X1b, FFT);
  // freq conv: A=fuwb[256][256], B^T=FFT -> Yt[(nh*65+wf)][256] bf16 (+BN+ReLU)
  k_gemm<256, 256, false, true, false><<<dim3(NCOLF / 128), dim3(512), 0, stream>>>(
      fuwb, (const void*)FFT, (void*)Yt, scF, shF);
  // inverse FFT + residual (x1 + fu + xs) -> ACC, in place over X1b
  k_ffti<<<dim3(NB * HH), dim3(256), 0, stream>>>(Yt, XSO, X1b);
  // conv2: A=w2b[256][128], B^T=ACC[(nhw)][128] -> out[(nhw)][256] f32 (NHWC)
  k_gemm<256, 128, false, false, true><<<dim3(NCOL1 / 128), dim3(512), 0, stream>>>(
      w2b, (const void*)X1b, (void*)out, nullptr, nullptr);
}

// Round 3
// 288.282 us; speedup vs baseline: 3.2150x; 1.5140x over previous
//
#include <hip/hip_runtime.h>
#include <math.h>

typedef __attribute__((ext_vector_type(8))) short short8;
typedef __attribute__((ext_vector_type(4))) float f32x4;

static __device__ __forceinline__ unsigned short f2b(float f){
  unsigned u = __float_as_uint(f);
  u = (u + 0x7FFFu + ((u >> 16) & 1u)) >> 16;
  return (unsigned short)u;
}
static __device__ __forceinline__ float b2f(unsigned short u){
  return __uint_as_float(((unsigned)u) << 16);
}

// ---------------- weight/matrix prep --------------------------------------------
// DFTf[144][128]: row m=2*wf+ri (wf<65): rfft/sqrt(128) coefficients; rows>=130 zero.
// IDFTf[128][160]: row w, col k2=2*wf+ri: irfft*sqrt(128) with Hermitian fold (alpha).
// DFTl[80][64], IDFTl[64][96]: same for W=64 (33 bins).
__global__ void k_wt(const float* __restrict__ w1, const float* __restrict__ fu_w,
                     const float* __restrict__ lfu_w, const float* __restrict__ w2,
                     const float* __restrict__ g1, const float* __restrict__ b1,
                     const float* __restrict__ m1, const float* __restrict__ v1,
                     const float* __restrict__ fg, const float* __restrict__ fb,
                     const float* __restrict__ fm, const float* __restrict__ fv,
                     const float* __restrict__ lg_, const float* __restrict__ lb_,
                     const float* __restrict__ lm_, const float* __restrict__ lv_,
                     unsigned short* __restrict__ w1b, unsigned short* __restrict__ fuwb,
                     unsigned short* __restrict__ lfuwb, unsigned short* __restrict__ w2b,
                     unsigned short* __restrict__ DFTf, unsigned short* __restrict__ IDFTf,
                     unsigned short* __restrict__ DFTl, unsigned short* __restrict__ IDFTl,
                     float* __restrict__ sc1, float* __restrict__ sh1,
                     float* __restrict__ scF, float* __restrict__ shF,
                     float* __restrict__ scL, float* __restrict__ shL) {
  int t = blockIdx.x * 256 + threadIdx.x;
  const float TPI = 6.283185307179586f;
  if (t < 32768) { w1b[t] = f2b(w1[t]); w2b[t] = f2b(w2[t]); }
  if (t < 65536) { fuwb[t] = f2b(fu_w[t]); lfuwb[t] = f2b(lfu_w[t]); }
  if (t < 18432) {                      // DFTf[144][128]
    int m = t >> 7, w = t & 127; float v = 0.f;
    if (m < 130) {
      int wf = m >> 1; int ph = (wf * w) & 127;
      float ang = TPI * (float)ph / 128.f;
      v = ((m & 1) ? -sinf(ang) : cosf(ang)) * 0.08838834764831845f;
    }
    DFTf[t] = f2b(v);
  }
  if (t < 20480) {                      // IDFTf[128][160]
    int w = t / 160, k2 = t % 160; float v = 0.f;
    if (k2 < 130) {
      int wf = k2 >> 1; float a = (wf == 0 || wf == 64) ? 1.f : 2.f;
      int ph = (wf * w) & 127;
      float ang = TPI * (float)ph / 128.f;
      v = ((k2 & 1) ? -a * sinf(ang) : a * cosf(ang)) * 0.08838834764831845f;
    }
    IDFTf[t] = f2b(v);
  }
  if (t < 5120) {                       // DFTl[80][64]
    int m = t >> 6, w = t & 63; float v = 0.f;
    if (m < 66) {
      int wf = m >> 1; int ph = (wf * w) & 63;
      float ang = TPI * (float)ph / 64.f;
      v = ((m & 1) ? -sinf(ang) : cosf(ang)) * 0.125f;
    }
    DFTl[t] = f2b(v);
  }
  if (t < 6144) {                       // IDFTl[64][96]
    int w = t / 96, k2 = t % 96; float v = 0.f;
    if (k2 < 66) {
      int wf = k2 >> 1; float a = (wf == 0 || wf == 32) ? 1.f : 2.f;
      int ph = (wf * w) & 63;
      float ang = TPI * (float)ph / 64.f;
      v = ((k2 & 1) ? -a * sinf(ang) : a * cosf(ang)) * 0.125f;
    }
    IDFTl[t] = f2b(v);
  }
  if (t < 128) { float s = g1[t] * rsqrtf(v1[t] + 1e-3f); sc1[t] = s; sh1[t] = b1[t] - m1[t] * s; }
  if (t < 256) { float s = fg[t] * rsqrtf(fv[t] + 1e-3f); scF[t] = s; shF[t] = fb[t] - fm[t] * s; }
  if (t < 256) { float s = lg_[t] * rsqrtf(lv_[t] + 1e-3f); scL[t] = s; shL[t] = lb_[t] - lm_[t] * s; }
}

// ------------- conv1: x NHWC f32 (K=256) -> X1c[nh][c][w] bf16 (+BN+ReLU) ---------
__global__ __launch_bounds__(256) void k_conv1(const unsigned short* __restrict__ A,
                                               const float* __restrict__ x,
                                               unsigned short* __restrict__ X1c,
                                               const float* __restrict__ scp,
                                               const float* __restrict__ shp) {
  int t = threadIdx.x; int wid = t >> 6, l = t & 63;
  int wm = wid >> 1, wn = wid & 1;
  int m0 = wm * 64; int lr = l & 15, lg = l >> 4;
  size_t nh = blockIdx.x;
  f32x4 acc[4][4];
  #pragma unroll
  for (int mt = 0; mt < 4; mt++)
    #pragma unroll
    for (int nt = 0; nt < 4; nt++) acc[mt][nt] = (f32x4){0.f, 0.f, 0.f, 0.f};
  for (int kk = 0; kk < 256; kk += 32) {
    short8 af[4], bf[4];
    #pragma unroll
    for (int mt = 0; mt < 4; mt++)
      af[mt] = *(const short8*)(A + (size_t)(m0 + 16 * mt + lr) * 256 + kk + lg * 8);
    #pragma unroll
    for (int nt = 0; nt < 4; nt++) {
      const float* bp = x + (nh * 128 + wn * 64 + 16 * nt + lr) * 256 + kk + lg * 8;
      float4 f0 = *(const float4*)bp, f1 = *(const float4*)(bp + 4);
      short8 bb;
      bb[0] = (short)f2b(f0.x); bb[1] = (short)f2b(f0.y);
      bb[2] = (short)f2b(f0.z); bb[3] = (short)f2b(f0.w);
      bb[4] = (short)f2b(f1.x); bb[5] = (short)f2b(f1.y);
      bb[6] = (short)f2b(f1.z); bb[7] = (short)f2b(f1.w);
      bf[nt] = bb;
    }
    #pragma unroll
    for (int mt = 0; mt < 4; mt++)
      #pragma unroll
      for (int nt = 0; nt < 4; nt++)
        acc[mt][nt] = __builtin_amdgcn_mfma_f32_16x16x32_bf16(af[mt], bf[nt], acc[mt][nt], 0, 0, 0);
  }
  #pragma unroll
  for (int nt = 0; nt < 4; nt++) {
    int w = wn * 64 + 16 * nt + lr;
    #pragma unroll
    for (int mt = 0; mt < 4; mt++) {
      int rb = m0 + 16 * mt + lg * 4;
      float4 s4 = *(const float4*)&scp[rb];
      float4 h4 = *(const float4*)&shp[rb];
      f32x4 v = acc[mt][nt];
      X1c[nh * 16384 + (size_t)(rb + 0) * 128 + w] = f2b(fmaxf(v[0] * s4.x + h4.x, 0.f));
      X1c[nh * 16384 + (size_t)(rb + 1) * 128 + w] = f2b(fmaxf(v[1] * s4.y + h4.y, 0.f));
      X1c[nh * 16384 + (size_t)(rb + 2) * 128 + w] = f2b(fmaxf(v[2] * s4.z + h4.z, 0.f));
      X1c[nh * 16384 + (size_t)(rb + 3) * 128 + w] = f2b(fmaxf(v[3] * s4.w + h4.w, 0.f));
    }
  }
}

// ------------- forward DFT (W=128): per nh, FF[(nh*65+wf)][2c+ri] -----------------
__global__ __launch_bounds__(256) void k_dftf(const unsigned short* __restrict__ DFTm,
                                              const unsigned short* __restrict__ X1c,
                                              unsigned short* __restrict__ FF) {
  int t = threadIdx.x; int wid = t >> 6, l = t & 63;
  int lr = l & 15, lg = l >> 4;
  size_t nh = blockIdx.x;
  int n0 = wid * 32;
  f32x4 acc[9][2];
  #pragma unroll
  for (int mt = 0; mt < 9; mt++) { acc[mt][0] = (f32x4){0,0,0,0}; acc[mt][1] = (f32x4){0,0,0,0}; }
  for (int kk = 0; kk < 128; kk += 32) {
    short8 af[9], bf[2];
    #pragma unroll
    for (int mt = 0; mt < 9; mt++)
      af[mt] = *(const short8*)(DFTm + (size_t)(16 * mt + lr) * 128 + kk + lg * 8);
    #pragma unroll
    for (int nt = 0; nt < 2; nt++)
      bf[nt] = *(const short8*)(X1c + nh * 16384 + (size_t)(n0 + 16 * nt + lr) * 128 + kk + lg * 8);
    #pragma unroll
    for (int mt = 0; mt < 9; mt++)
      #pragma unroll
      for (int nt = 0; nt < 2; nt++)
        acc[mt][nt] = __builtin_amdgcn_mfma_f32_16x16x32_bf16(af[mt], bf[nt], acc[mt][nt], 0, 0, 0);
  }
  #pragma unroll
  for (int nt = 0; nt < 2; nt++) {
    int c = n0 + 16 * nt + lr;
    #pragma unroll
    for (int mt = 0; mt < 9; mt++) {
      int rb = 16 * mt + lg * 4;
      int wf0 = rb >> 1;
      f32x4 v = acc[mt][nt];
      if (wf0 < 65) {
        unsigned pk = (unsigned)f2b(v[0]) | ((unsigned)f2b(v[1]) << 16);
        *(unsigned*)(FF + (nh * 65 + wf0) * 256 + 2 * c) = pk;
      }
      if (wf0 + 1 < 65) {
        unsigned pk = (unsigned)f2b(v[2]) | ((unsigned)f2b(v[3]) << 16);
        *(unsigned*)(FF + (nh * 65 + wf0 + 1) * 256 + 2 * c) = pk;
      }
    }
  }
}

// ------------- freq conv 256->256 + BN + ReLU, permuted store Y[nh][co'][2wf+ri] ---
template<int DIVN, int PADK>
__global__ __launch_bounds__(512) void k_conv_perm(const unsigned short* __restrict__ A,
                                                   const unsigned short* __restrict__ B,
                                                   unsigned short* __restrict__ Y,
                                                   const float* __restrict__ scp,
                                                   const float* __restrict__ shp) {
  int t = threadIdx.x; int wid = t >> 6, l = t & 63;
  int wm = wid >> 1, wn = wid & 1;
  int m0 = wm * 64; size_t col0 = (size_t)blockIdx.x * 128 + wn * 64;
  int lr = l & 15, lg = l >> 4;
  f32x4 acc[4][4];
  #pragma unroll
  for (int mt = 0; mt < 4; mt++)
    #pragma unroll
    for (int nt = 0; nt < 4; nt++) acc[mt][nt] = (f32x4){0.f, 0.f, 0.f, 0.f};
  for (int kk = 0; kk < 256; kk += 32) {
    short8 af[4], bf[4];
    #pragma unroll
    for (int mt = 0; mt < 4; mt++)
      af[mt] = *(const short8*)(A + (size_t)(m0 + 16 * mt + lr) * 256 + kk + lg * 8);
    #pragma unroll
    for (int nt = 0; nt < 4; nt++)
      bf[nt] = *(const short8*)(B + (col0 + 16 * nt + lr) * 256 + kk + lg * 8);
    #pragma unroll
    for (int mt = 0; mt < 4; mt++)
      #pragma unroll
      for (int nt = 0; nt < 4; nt++)
        acc[mt][nt] = __builtin_amdgcn_mfma_f32_16x16x32_bf16(af[mt], bf[nt], acc[mt][nt], 0, 0, 0);
  }
  #pragma unroll
  for (int nt = 0; nt < 4; nt++) {
    int col = (int)(col0 + 16 * nt + lr);
    int nh = col / DIVN, wf = col % DIVN;
    #pragma unroll
    for (int mt = 0; mt < 4; mt++) {
      int rb = m0 + 16 * mt + lg * 4;
      float4 s4 = *(const float4*)&scp[rb];
      float4 h4 = *(const float4*)&shp[rb];
      f32x4 v = acc[mt][nt];
      float v0 = fmaxf(v[0] * s4.x + h4.x, 0.f);
      float v1 = fmaxf(v[1] * s4.y + h4.y, 0.f);
      float v2 = fmaxf(v[2] * s4.z + h4.z, 0.f);
      float v3 = fmaxf(v[3] * s4.w + h4.w, 0.f);
      int co0 = rb >> 1;
      unsigned p0 = (unsigned)f2b(v0) | ((unsigned)f2b(v1) << 16);
      unsigned p1 = (unsigned)f2b(v2) | ((unsigned)f2b(v3) << 16);
      *(unsigned*)(Y + ((size_t)nh * 128 + co0) * PADK + 2 * wf) = p0;
      *(unsigned*)(Y + ((size_t)nh * 128 + co0 + 1) * PADK + 2 * wf) = p1;
    }
  }
}

// ------------- inverse DFT (W=128) + residual(x + xs) -> ACC[(nhw)][c] bf16 -------
__global__ __launch_bounds__(256) void k_idftf(const unsigned short* __restrict__ IDFTm,
                                               const unsigned short* __restrict__ Yc,
                                               const unsigned short* __restrict__ X1c,
                                               const unsigned short* __restrict__ XSO,
                                               unsigned short* __restrict__ ACC) {
  int t = threadIdx.x; int wid = t >> 6, l = t & 63;
  int lr = l & 15, lg = l >> 4;
  size_t nh = blockIdx.x;
  int n = (int)(nh >> 7), h = (int)(nh & 127);
  int n0 = wid * 32;
  f32x4 acc[8][2];
  #pragma unroll
  for (int mt = 0; mt < 8; mt++) { acc[mt][0] = (f32x4){0,0,0,0}; acc[mt][1] = (f32x4){0,0,0,0}; }
  for (int kk = 0; kk < 160; kk += 32) {
    short8 af[8], bf[2];
    #pragma unroll
    for (int mt = 0; mt < 8; mt++)
      af[mt] = *(const short8*)(IDFTm + (size_t)(16 * mt + lr) * 160 + kk + lg * 8);
    #pragma unroll
    for (int nt = 0; nt < 2; nt++)
      bf[nt] = *(const short8*)(Yc + ((size_t)nh * 128 + n0 + 16 * nt + lr) * 160 + kk + lg * 8);
    #pragma unroll
    for (int mt = 0; mt < 8; mt++)
      #pragma unroll
      for (int nt = 0; nt < 2; nt++)
        acc[mt][nt] = __builtin_amdgcn_mfma_f32_16x16x32_bf16(af[mt], bf[nt], acc[mt][nt], 0, 0, 0);
  }
  #pragma unroll
  for (int nt = 0; nt < 2; nt++) {
    int co = n0 + 16 * nt + lr;
    const unsigned short* xr = X1c + nh * 16384 + (size_t)co * 128;
    const unsigned short* xs = XSO + (((size_t)n * 128 + co) * 64 + (h & 63)) * 64;
    #pragma unroll
    for (int mt = 0; mt < 8; mt++) {
      int rb = 16 * mt + lg * 4;
      ushort4 rx = *(const ushort4*)(xr + rb);
      ushort4 rs = *(const ushort4*)(xs + (rb & 63));
      f32x4 v = acc[mt][nt];
      ACC[(nh * 128 + rb + 0) * 128 + co] = f2b(v[0] + b2f(rx.x) + b2f(rs.x));
      ACC[(nh * 128 + rb + 1) * 128 + co] = f2b(v[1] + b2f(rx.y) + b2f(rs.y));
      ACC[(nh * 128 + rb + 2) * 128 + co] = f2b(v[2] + b2f(rx.z) + b2f(rs.z));
      ACC[(nh * 128 + rb + 3) * 128 + co] = f2b(v[3] + b2f(rx.w) + b2f(rs.w));
    }
  }
}

// ------------- local FU forward DFT (W=64): FFl[((n*64+h2)*33+wf)][2c2+ri] --------
__global__ __launch_bounds__(256) void k_dftl(const unsigned short* __restrict__ DFTm,
                                              const unsigned short* __restrict__ X1c,
                                              unsigned short* __restrict__ FFl) {
  int t = threadIdx.x; int wid = t >> 6, l = t & 63;
  int lr = l & 15, lg = l >> 4;
  int b = blockIdx.x; int n = b >> 6, h2 = b & 63;
  int n0 = wid * 32;
  f32x4 acc[5][2];
  #pragma unroll
  for (int mt = 0; mt < 5; mt++) { acc[mt][0] = (f32x4){0,0,0,0}; acc[mt][1] = (f32x4){0,0,0,0}; }
  for (int kk = 0; kk < 64; kk += 32) {
    short8 af[5], bf[2];
    #pragma unroll
    for (int mt = 0; mt < 5; mt++)
      af[mt] = *(const short8*)(DFTm + (size_t)(16 * mt + lr) * 64 + kk + lg * 8);
    #pragma unroll
    for (int nt = 0; nt < 2; nt++) {
      int c2 = n0 + 16 * nt + lr;
      int wb = c2 >> 6, hb = (c2 >> 5) & 1, c0 = c2 & 31;
      bf[nt] = *(const short8*)(X1c + ((size_t)(n * 128 + hb * 64 + h2) * 128 + c0) * 128
                                + wb * 64 + kk + lg * 8);
    }
    #pragma unroll
    for (int mt = 0; mt < 5; mt++)
      #pragma unroll
      for (int nt = 0; nt < 2; nt++)
        acc[mt][nt] = __builtin_amdgcn_mfma_f32_16x16x32_bf16(af[mt], bf[nt], acc[mt][nt], 0, 0, 0);
  }
  #pragma unroll
  for (int nt = 0; nt < 2; nt++) {
    int c2 = n0 + 16 * nt + lr;
    #pragma unroll
    for (int mt = 0; mt < 5; mt++) {
      int rb = 16 * mt + lg * 4;
      int wf0 = rb >> 1;
      f32x4 v = acc[mt][nt];
      if (wf0 < 33) {
        unsigned pk = (unsigned)f2b(v[0]) | ((unsigned)f2b(v[1]) << 16);
        *(unsigned*)(FFl + ((size_t)((n * 64 + h2) * 33 + wf0)) * 256 + 2 * c2) = pk;
      }
      if (wf0 + 1 < 33) {
        unsigned pk = (unsigned)f2b(v[2]) | ((unsigned)f2b(v[3]) << 16);
        *(unsigned*)(FFl + ((size_t)((n * 64 + h2) * 33 + wf0 + 1)) * 256 + 2 * c2) = pk;
      }
    }
  }
}

// ------------- local FU inverse DFT (W=64) -> XSO[n][c][h2][w2] bf16 --------------
__global__ __launch_bounds__(256) void k_idftl(const unsigned short* __restrict__ IDFTm,
                                               const unsigned short* __restrict__ Ycl,
                                               unsigned short* __restrict__ XSO) {
  int t = threadIdx.x; int wid = t >> 6, l = t & 63;
  int lr = l & 15, lg = l >> 4;
  int b = blockIdx.x; int n = b >> 6, h2 = b & 63;
  int n0 = wid * 32;
  f32x4 acc[4][2];
  #pragma unroll
  for (int mt = 0; mt < 4; mt++) { acc[mt][0] = (f32x4){0,0,0,0}; acc[mt][1] = (f32x4){0,0,0,0}; }
  for (int kk = 0; kk < 96; kk += 32) {
    short8 af[4], bf[2];
    #pragma unroll
    for (int mt = 0; mt < 4; mt++)
      af[mt] = *(const short8*)(IDFTm + (size_t)(16 * mt + lr) * 96 + kk + lg * 8);
    #pragma unroll
    for (int nt = 0; nt < 2; nt++)
      bf[nt] = *(const short8*)(Ycl + ((size_t)(n * 64 + h2) * 128 + n0 + 16 * nt + lr) * 96
                                + kk + lg * 8);
    #pragma unroll
    for (int mt = 0; mt < 4; mt++)
      #pragma unroll
      for (int nt = 0; nt < 2; nt++)
        acc[mt][nt] = __builtin_amdgcn_mfma_f32_16x16x32_bf16(af[mt], bf[nt], acc[mt][nt], 0, 0, 0);
  }
  #pragma unroll
  for (int nt = 0; nt < 2; nt++) {
    int co = n0 + 16 * nt + lr;
    #pragma unroll
    for (int mt = 0; mt < 4; mt++) {
      int rb = 16 * mt + lg * 4;
      f32x4 v = acc[mt][nt];
      ushort4 o;
      o.x = f2b(v[0]); o.y = f2b(v[1]); o.z = f2b(v[2]); o.w = f2b(v[3]);
      *(ushort4*)(XSO + (((size_t)n * 128 + co) * 64 + h2) * 64 + rb) = o;
    }
  }
}

// ------------- conv2: ACC[(nhw)][128] -> out[(nhw)][256] f32 ----------------------
__global__ __launch_bounds__(512) void k_conv2(const unsigned short* __restrict__ A,
                                               const unsigned short* __restrict__ B,
                                               float* __restrict__ out) {
  int t = threadIdx.x; int wid = t >> 6, l = t & 63;
  int wm = wid >> 1, wn = wid & 1;
  int m0 = wm * 64; size_t col0 = (size_t)blockIdx.x * 128 + wn * 64;
  int lr = l & 15, lg = l >> 4;
  f32x4 acc[4][4];
  #pragma unroll
  for (int mt = 0; mt < 4; mt++)
    #pragma unroll
    for (int nt = 0; nt < 4; nt++) acc[mt][nt] = (f32x4){0.f, 0.f, 0.f, 0.f};
  for (int kk = 0; kk < 128; kk += 32) {
    short8 af[4], bf[4];
    #pragma unroll
    for (int mt = 0; mt < 4; mt++)
      af[mt] = *(const short8*)(A + (size_t)(m0 + 16 * mt + lr) * 128 + kk + lg * 8);
    #pragma unroll
    for (int nt = 0; nt < 4; nt++)
      bf[nt] = *(const short8*)(B + (col0 + 16 * nt + lr) * 128 + kk + lg * 8);
    #pragma unroll
    for (int mt = 0; mt < 4; mt++)
      #pragma unroll
      for (int nt = 0; nt < 4; nt++)
        acc[mt][nt] = __builtin_amdgcn_mfma_f32_16x16x32_bf16(af[mt], bf[nt], acc[mt][nt], 0, 0, 0);
  }
  #pragma unroll
  for (int nt = 0; nt < 4; nt++) {
    size_t col = col0 + 16 * nt + lr;
    #pragma unroll
    for (int mt = 0; mt < 4; mt++) {
      int rb = m0 + 16 * mt + lg * 4;
      f32x4 v = acc[mt][nt];
      float4 o; o.x = v[0]; o.y = v[1]; o.z = v[2]; o.w = v[3];
      *(float4*)(out + col * 256 + rb) = o;
    }
  }
}

extern "C" void kernel_launch(void* const* d_in, const int* in_sizes, int n_in,
                              void* d_out, int out_size, void* d_ws, size_t ws_size,
                              hipStream_t stream) {
  const float* x     = (const float*)d_in[0];
  const float* w1    = (const float*)d_in[1];
  const float* g1    = (const float*)d_in[2];
  const float* b1    = (const float*)d_in[3];
  const float* m1    = (const float*)d_in[4];
  const float* v1    = (const float*)d_in[5];
  const float* fu_w  = (const float*)d_in[6];
  const float* fu_g  = (const float*)d_in[7];
  const float* fu_b  = (const float*)d_in[8];
  const float* fu_m  = (const float*)d_in[9];
  const float* fu_v  = (const float*)d_in[10];
  const float* lfu_w = (const float*)d_in[11];
  const float* lfu_g = (const float*)d_in[12];
  const float* lfu_b = (const float*)d_in[13];
  const float* lfu_m = (const float*)d_in[14];
  const float* lfu_v = (const float*)d_in[15];
  const float* w2    = (const float*)d_in[16];
  float* out = (float*)d_out;

  char* p = (char*)d_ws;
  unsigned short* X1c = (unsigned short*)p; p += 33554432;         // [nh][c][w] bf16
  unsigned short* XSO = (unsigned short*)p; p += 8388608;          // [n][c][h2][w2] bf16
  char* bufC = p; p += 41943040;                                   // FFl, then Yc
  char* bufD = p; p += 34078720;                                   // Ycl, then FF, then ACC
  unsigned short* FFl = (unsigned short*)bufC;                     // 16896*256
  unsigned short* Yc  = (unsigned short*)bufC;                     // 1024*128*160
  unsigned short* Ycl = (unsigned short*)bufD;                     // 512*128*96
  unsigned short* FF  = (unsigned short*)bufD;                     // 66560*256
  unsigned short* ACC = (unsigned short*)bufD;                     // 131072*128
  unsigned short* w1b   = (unsigned short*)p; p += 65536;
  unsigned short* fuwb  = (unsigned short*)p; p += 131072;
  unsigned short* lfuwb = (unsigned short*)p; p += 131072;
  unsigned short* w2b   = (unsigned short*)p; p += 65536;
  unsigned short* DFTf  = (unsigned short*)p; p += 36864;
  unsigned short* IDFTf = (unsigned short*)p; p += 40960;
  unsigned short* DFTl  = (unsigned short*)p; p += 10240;
  unsigned short* IDFTl = (unsigned short*)p; p += 12288;
  float* sc1 = (float*)p; p += 512;
  float* sh1 = (float*)p; p += 512;
  float* scF = (float*)p; p += 1024;
  float* shF = (float*)p; p += 1024;
  float* scL = (float*)p; p += 1024;
  float* shL = (float*)p; p += 1024;

  k_wt<<<dim3(256), dim3(256), 0, stream>>>(w1, fu_w, lfu_w, w2, g1, b1, m1, v1,
                                            fu_g, fu_b, fu_m, fu_v, lfu_g, lfu_b, lfu_m, lfu_v,
                                            w1b, fuwb, lfuwb, w2b, DFTf, IDFTf, DFTl, IDFTl,
                                            sc1, sh1, scF, shF, scL, shL);
  k_conv1<<<dim3(1024), dim3(256), 0, stream>>>(w1b, x, X1c, sc1, sh1);
  k_dftl<<<dim3(512), dim3(256), 0, stream>>>(DFTl, X1c, FFl);
  k_conv_perm<33, 96><<<dim3(132), dim3(512), 0, stream>>>(lfuwb, FFl, Ycl, scL, shL);
  k_idftl<<<dim3(512), dim3(256), 0, stream>>>(IDFTl, Ycl, XSO);
  k_dftf<<<dim3(1024), dim3(256), 0, stream>>>(DFTf, X1c, FF);
  k_conv_perm<65, 160><<<dim3(520), dim3(512), 0, stream>>>(fuwb, FF, Yc, scF, shF);
  k_idftf<<<dim3(1024), dim3(256), 0, stream>>>(IDFTf, Yc, X1c, XSO, ACC);
  k_conv2<<<dim3(1024), dim3(512), 0, stream>>>(w2b, ACC, out);
}

// Round 4
// 216.718 us; speedup vs baseline: 4.2767x; 1.3302x over previous
//
#include <hip/hip_runtime.h>
#include <math.h>

typedef __attribute__((ext_vector_type(8))) short short8;
typedef __attribute__((ext_vector_type(4))) float f32x4;

static __device__ __forceinline__ unsigned short f2b(float f){
  unsigned u = __float_as_uint(f);
  u = (u + 0x7FFFu + ((u >> 16) & 1u)) >> 16;
  return (unsigned short)u;
}
static __device__ __forceinline__ float b2f(unsigned short u){
  return __uint_as_float(((unsigned)u) << 16);
}

// async global->LDS, 16B per lane. lds ptr wave-uniform; global per-lane.
static __device__ __forceinline__ void gl16(const void* g, void* l) {
  __builtin_amdgcn_global_load_lds(
      (const __attribute__((address_space(1))) void*)g,
      (__attribute__((address_space(3))) void*)l, 16, 0, 0);
}

// ---------------- weight/matrix prep --------------------------------------------
__global__ void k_wt(const float* __restrict__ w1, const float* __restrict__ fu_w,
                     const float* __restrict__ lfu_w, const float* __restrict__ w2,
                     const float* __restrict__ g1, const float* __restrict__ b1,
                     const float* __restrict__ m1, const float* __restrict__ v1,
                     const float* __restrict__ fg, const float* __restrict__ fb,
                     const float* __restrict__ fm, const float* __restrict__ fv,
                     const float* __restrict__ lg_, const float* __restrict__ lb_,
                     const float* __restrict__ lm_, const float* __restrict__ lv_,
                     unsigned short* __restrict__ w1b, unsigned short* __restrict__ fuwb,
                     unsigned short* __restrict__ lfuwb, unsigned short* __restrict__ w2b,
                     unsigned short* __restrict__ DFTf, unsigned short* __restrict__ IDFTf,
                     unsigned short* __restrict__ DFTl, unsigned short* __restrict__ IDFTl,
                     float* __restrict__ sc1, float* __restrict__ sh1,
                     float* __restrict__ scF, float* __restrict__ shF,
                     float* __restrict__ scL, float* __restrict__ shL) {
  int t = blockIdx.x * 256 + threadIdx.x;
  const float TPI = 6.283185307179586f;
  if (t < 32768) { w1b[t] = f2b(w1[t]); w2b[t] = f2b(w2[t]); }
  if (t < 65536) { fuwb[t] = f2b(fu_w[t]); lfuwb[t] = f2b(lfu_w[t]); }
  if (t < 18432) {                      // DFTf[144][128]
    int m = t >> 7, w = t & 127; float v = 0.f;
    if (m < 130) {
      int wf = m >> 1; int ph = (wf * w) & 127;
      float ang = TPI * (float)ph / 128.f;
      v = ((m & 1) ? -sinf(ang) : cosf(ang)) * 0.08838834764831845f;
    }
    DFTf[t] = f2b(v);
  }
  if (t < 20480) {                      // IDFTf[128][160]
    int w = t / 160, k2 = t % 160; float v = 0.f;
    if (k2 < 130) {
      int wf = k2 >> 1; float a = (wf == 0 || wf == 64) ? 1.f : 2.f;
      int ph = (wf * w) & 127;
      float ang = TPI * (float)ph / 128.f;
      v = ((k2 & 1) ? -a * sinf(ang) : a * cosf(ang)) * 0.08838834764831845f;
    }
    IDFTf[t] = f2b(v);
  }
  if (t < 5120) {                       // DFTl[80][64]
    int m = t >> 6, w = t & 63; float v = 0.f;
    if (m < 66) {
      int wf = m >> 1; int ph = (wf * w) & 63;
      float ang = TPI * (float)ph / 64.f;
      v = ((m & 1) ? -sinf(ang) : cosf(ang)) * 0.125f;
    }
    DFTl[t] = f2b(v);
  }
  if (t < 6144) {                       // IDFTl[64][96]
    int w = t / 96, k2 = t % 96; float v = 0.f;
    if (k2 < 66) {
      int wf = k2 >> 1; float a = (wf == 0 || wf == 32) ? 1.f : 2.f;
      int ph = (wf * w) & 63;
      float ang = TPI * (float)ph / 64.f;
      v = ((k2 & 1) ? -a * sinf(ang) : a * cosf(ang)) * 0.125f;
    }
    IDFTl[t] = f2b(v);
  }
  if (t < 128) { float s = g1[t] * rsqrtf(v1[t] + 1e-3f); sc1[t] = s; sh1[t] = b1[t] - m1[t] * s; }
  if (t < 256) { float s = fg[t] * rsqrtf(fv[t] + 1e-3f); scF[t] = s; shF[t] = fb[t] - fm[t] * s; }
  if (t < 256) { float s = lg_[t] * rsqrtf(lv_[t] + 1e-3f); scL[t] = s; shL[t] = lb_[t] - lm_[t] * s; }
}

// ------------- conv1: x NHWC f32 (K=256) -> X1c[nh][c][w] bf16 (+BN+ReLU) ---------
__global__ __launch_bounds__(256) void k_conv1(const unsigned short* __restrict__ A,
                                               const float* __restrict__ x,
                                               unsigned short* __restrict__ X1c,
                                               const float* __restrict__ scp,
                                               const float* __restrict__ shp) {
  __shared__ __align__(16) unsigned short A_s[128 * 256];  // 64 KB
  __shared__ __align__(16) float B_s[128 * 32];            // 16 KB
  int t = threadIdx.x; int wid = t >> 6, l = t & 63;
  int wm = wid >> 1, wn = wid & 1;
  int m0 = wm * 64; int lr = l & 15, lg = l >> 4;
  size_t nh = blockIdx.x;
  int wb_ = (t >> 6) * 1024;
  const char* Ab = (const char*)A;
  const char* xrow = (const char*)(x + nh * 128 * 256);
  #pragma unroll
  for (int i = 0; i < 16; i++)
    gl16(Ab + i * 4096 + t * 16, (char*)A_s + i * 4096 + wb_);
  f32x4 acc[4][4];
  #pragma unroll
  for (int mt = 0; mt < 4; mt++)
    #pragma unroll
    for (int nt = 0; nt < 4; nt++) acc[mt][nt] = (f32x4){0.f, 0.f, 0.f, 0.f};
  int c8 = t >> 3, q8 = t & 7;
  for (int kk = 0; kk < 256; kk += 32) {
    #pragma unroll
    for (int i = 0; i < 4; i++)
      gl16(xrow + (size_t)(i * 32 + c8) * 1024 + kk * 4 + q8 * 16,
           (char*)B_s + i * 4096 + wb_);
    __syncthreads();
    short8 af[4], bf[4];
    #pragma unroll
    for (int mt = 0; mt < 4; mt++)
      af[mt] = *(const short8*)((const char*)A_s + (size_t)(m0 + 16 * mt + lr) * 512 + kk * 2 + lg * 16);
    #pragma unroll
    for (int nt = 0; nt < 4; nt++) {
      const float* bp = B_s + (wn * 64 + 16 * nt + lr) * 32 + lg * 8;
      float4 f0 = *(const float4*)bp, f1 = *(const float4*)(bp + 4);
      short8 bb;
      bb[0] = (short)f2b(f0.x); bb[1] = (short)f2b(f0.y);
      bb[2] = (short)f2b(f0.z); bb[3] = (short)f2b(f0.w);
      bb[4] = (short)f2b(f1.x); bb[5] = (short)f2b(f1.y);
      bb[6] = (short)f2b(f1.z); bb[7] = (short)f2b(f1.w);
      bf[nt] = bb;
    }
    #pragma unroll
    for (int mt = 0; mt < 4; mt++)
      #pragma unroll
      for (int nt = 0; nt < 4; nt++)
        acc[mt][nt] = __builtin_amdgcn_mfma_f32_16x16x32_bf16(af[mt], bf[nt], acc[mt][nt], 0, 0, 0);
    __syncthreads();
  }
  #pragma unroll
  for (int nt = 0; nt < 4; nt++) {
    int w = wn * 64 + 16 * nt + lr;
    #pragma unroll
    for (int mt = 0; mt < 4; mt++) {
      int rb = m0 + 16 * mt + lg * 4;
      float4 s4 = *(const float4*)&scp[rb];
      float4 h4 = *(const float4*)&shp[rb];
      f32x4 v = acc[mt][nt];
      X1c[nh * 16384 + (size_t)(rb + 0) * 128 + w] = f2b(fmaxf(v[0] * s4.x + h4.x, 0.f));
      X1c[nh * 16384 + (size_t)(rb + 1) * 128 + w] = f2b(fmaxf(v[1] * s4.y + h4.y, 0.f));
      X1c[nh * 16384 + (size_t)(rb + 2) * 128 + w] = f2b(fmaxf(v[2] * s4.z + h4.z, 0.f));
      X1c[nh * 16384 + (size_t)(rb + 3) * 128 + w] = f2b(fmaxf(v[3] * s4.w + h4.w, 0.f));
    }
  }
}

// ------------- forward DFT (W=128): all-LDS-resident, per nh ----------------------
__global__ __launch_bounds__(256) void k_dftf(const unsigned short* __restrict__ DFTm,
                                              const unsigned short* __restrict__ X1c,
                                              unsigned short* __restrict__ FF) {
  __shared__ __align__(16) unsigned short A_s[144 * 128];  // 36 KB
  __shared__ __align__(16) unsigned short B_s[128 * 128];  // 32 KB
  int t = threadIdx.x; int wid = t >> 6, l = t & 63;
  int lr = l & 15, lg = l >> 4;
  size_t nh = blockIdx.x;
  int n0 = wid * 32;
  int wb_ = (t >> 6) * 1024;
  const char* Ab = (const char*)DFTm;
  const char* Bb = (const char*)(X1c + nh * 16384);
  #pragma unroll
  for (int i = 0; i < 9; i++) gl16(Ab + i * 4096 + t * 16, (char*)A_s + i * 4096 + wb_);
  #pragma unroll
  for (int i = 0; i < 8; i++) gl16(Bb + i * 4096 + t * 16, (char*)B_s + i * 4096 + wb_);
  __syncthreads();
  f32x4 acc[9][2];
  #pragma unroll
  for (int mt = 0; mt < 9; mt++) { acc[mt][0] = (f32x4){0,0,0,0}; acc[mt][1] = (f32x4){0,0,0,0}; }
  for (int kk = 0; kk < 128; kk += 32) {
    short8 af[9], bf[2];
    #pragma unroll
    for (int mt = 0; mt < 9; mt++)
      af[mt] = *(const short8*)((const char*)A_s + (size_t)(16 * mt + lr) * 256 + kk * 2 + lg * 16);
    #pragma unroll
    for (int nt = 0; nt < 2; nt++)
      bf[nt] = *(const short8*)((const char*)B_s + (size_t)(n0 + 16 * nt + lr) * 256 + kk * 2 + lg * 16);
    #pragma unroll
    for (int mt = 0; mt < 9; mt++)
      #pragma unroll
      for (int nt = 0; nt < 2; nt++)
        acc[mt][nt] = __builtin_amdgcn_mfma_f32_16x16x32_bf16(af[mt], bf[nt], acc[mt][nt], 0, 0, 0);
  }
  #pragma unroll
  for (int nt = 0; nt < 2; nt++) {
    int c = n0 + 16 * nt + lr;
    #pragma unroll
    for (int mt = 0; mt < 9; mt++) {
      int rb = 16 * mt + lg * 4;
      int wf0 = rb >> 1;
      f32x4 v = acc[mt][nt];
      if (wf0 < 65) {
        unsigned pk = (unsigned)f2b(v[0]) | ((unsigned)f2b(v[1]) << 16);
        *(unsigned*)(FF + (nh * 65 + wf0) * 256 + 2 * c) = pk;
      }
      if (wf0 + 1 < 65) {
        unsigned pk = (unsigned)f2b(v[2]) | ((unsigned)f2b(v[3]) << 16);
        *(unsigned*)(FF + (nh * 65 + wf0 + 1) * 256 + 2 * c) = pk;
      }
    }
  }
}

// ------------- freq conv 256->256 + BN + ReLU, BK=64 LDS staging ------------------
template<int DIVN, int PADK>
__global__ __launch_bounds__(512) void k_conv_perm(const unsigned short* __restrict__ A,
                                                   const unsigned short* __restrict__ B,
                                                   unsigned short* __restrict__ Y,
                                                   const float* __restrict__ scp,
                                                   const float* __restrict__ shp) {
  __shared__ __align__(16) unsigned short A_s[256 * 64];   // 32 KB
  __shared__ __align__(16) unsigned short B_s[128 * 64];   // 16 KB
  int t = threadIdx.x; int wid = t >> 6, l = t & 63;
  int wm = wid >> 1, wn = wid & 1;
  int m0 = wm * 64; size_t col0 = (size_t)blockIdx.x * 128 + wn * 64;
  int lr = l & 15, lg = l >> 4;
  int wb_ = (t >> 6) * 1024;
  const char* Ab = (const char*)A;
  const char* Bb = (const char*)B + (size_t)blockIdx.x * 128 * 512;
  f32x4 acc[4][4];
  #pragma unroll
  for (int mt = 0; mt < 4; mt++)
    #pragma unroll
    for (int nt = 0; nt < 4; nt++) acc[mt][nt] = (f32x4){0.f, 0.f, 0.f, 0.f};
  int r8 = t >> 3, q8 = t & 7;
  for (int kk = 0; kk < 256; kk += 64) {
    if (kk) __syncthreads();
    #pragma unroll
    for (int i = 0; i < 4; i++)
      gl16(Ab + (size_t)(i * 64 + r8) * 512 + kk * 2 + q8 * 16, (char*)A_s + i * 8192 + wb_);
    #pragma unroll
    for (int i = 0; i < 2; i++)
      gl16(Bb + (size_t)(i * 64 + r8) * 512 + kk * 2 + q8 * 16, (char*)B_s + i * 8192 + wb_);
    __syncthreads();
    #pragma unroll
    for (int ks = 0; ks < 2; ks++) {
      short8 af[4], bf[4];
      #pragma unroll
      for (int mt = 0; mt < 4; mt++)
        af[mt] = *(const short8*)((const char*)A_s + (size_t)(m0 + 16 * mt + lr) * 128 + ks * 64 + lg * 16);
      #pragma unroll
      for (int nt = 0; nt < 4; nt++)
        bf[nt] = *(const short8*)((const char*)B_s + (size_t)(wn * 64 + 16 * nt + lr) * 128 + ks * 64 + lg * 16);
      #pragma unroll
      for (int mt = 0; mt < 4; mt++)
        #pragma unroll
        for (int nt = 0; nt < 4; nt++)
          acc[mt][nt] = __builtin_amdgcn_mfma_f32_16x16x32_bf16(af[mt], bf[nt], acc[mt][nt], 0, 0, 0);
    }
  }
  #pragma unroll
  for (int nt = 0; nt < 4; nt++) {
    int col = (int)(col0 + 16 * nt + lr);
    int nh = col / DIVN, wf = col % DIVN;
    #pragma unroll
    for (int mt = 0; mt < 4; mt++) {
      int rb = m0 + 16 * mt + lg * 4;
      float4 s4 = *(const float4*)&scp[rb];
      float4 h4 = *(const float4*)&shp[rb];
      f32x4 v = acc[mt][nt];
      float v0 = fmaxf(v[0] * s4.x + h4.x, 0.f);
      float v1 = fmaxf(v[1] * s4.y + h4.y, 0.f);
      float v2 = fmaxf(v[2] * s4.z + h4.z, 0.f);
      float v3 = fmaxf(v[3] * s4.w + h4.w, 0.f);
      int co0 = rb >> 1;
      unsigned p0 = (unsigned)f2b(v0) | ((unsigned)f2b(v1) << 16);
      unsigned p1 = (unsigned)f2b(v2) | ((unsigned)f2b(v3) << 16);
      *(unsigned*)(Y + ((size_t)nh * 128 + co0) * PADK + 2 * wf) = p0;
      *(unsigned*)(Y + ((size_t)nh * 128 + co0 + 1) * PADK + 2 * wf) = p1;
    }
  }
}

// ------------- inverse DFT (W=128) + residual -> ACC[(nhw)][c], all-LDS -----------
__global__ __launch_bounds__(256) void k_idftf(const unsigned short* __restrict__ IDFTm,
                                               const unsigned short* __restrict__ Yc,
                                               const unsigned short* __restrict__ X1c,
                                               const unsigned short* __restrict__ XSO,
                                               unsigned short* __restrict__ ACC) {
  __shared__ __align__(16) unsigned short A_s[128 * 160];  // 40 KB
  __shared__ __align__(16) unsigned short B_s[128 * 160];  // 40 KB
  int t = threadIdx.x; int wid = t >> 6, l = t & 63;
  int lr = l & 15, lg = l >> 4;
  size_t nh = blockIdx.x;
  int n = (int)(nh >> 7), h = (int)(nh & 127);
  int n0 = wid * 32;
  int wb_ = (t >> 6) * 1024;
  const char* Ab = (const char*)IDFTm;
  const char* Bb = (const char*)(Yc + nh * 128 * 160);
  #pragma unroll
  for (int i = 0; i < 10; i++) gl16(Ab + i * 4096 + t * 16, (char*)A_s + i * 4096 + wb_);
  #pragma unroll
  for (int i = 0; i < 10; i++) gl16(Bb + i * 4096 + t * 16, (char*)B_s + i * 4096 + wb_);
  __syncthreads();
  f32x4 acc[8][2];
  #pragma unroll
  for (int mt = 0; mt < 8; mt++) { acc[mt][0] = (f32x4){0,0,0,0}; acc[mt][1] = (f32x4){0,0,0,0}; }
  for (int kk = 0; kk < 160; kk += 32) {
    short8 af[8], bf[2];
    #pragma unroll
    for (int mt = 0; mt < 8; mt++)
      af[mt] = *(const short8*)((const char*)A_s + (size_t)(16 * mt + lr) * 320 + kk * 2 + lg * 16);
    #pragma unroll
    for (int nt = 0; nt < 2; nt++)
      bf[nt] = *(const short8*)((const char*)B_s + (size_t)(n0 + 16 * nt + lr) * 320 + kk * 2 + lg * 16);
    #pragma unroll
    for (int mt = 0; mt < 8; mt++)
      #pragma unroll
      for (int nt = 0; nt < 2; nt++)
        acc[mt][nt] = __builtin_amdgcn_mfma_f32_16x16x32_bf16(af[mt], bf[nt], acc[mt][nt], 0, 0, 0);
  }
  #pragma unroll
  for (int nt = 0; nt < 2; nt++) {
    int co = n0 + 16 * nt + lr;
    const unsigned short* xr = X1c + nh * 16384 + (size_t)co * 128;
    const unsigned short* xs = XSO + (((size_t)n * 128 + co) * 64 + (h & 63)) * 64;
    #pragma unroll
    for (int mt = 0; mt < 8; mt++) {
      int rb = 16 * mt + lg * 4;
      ushort4 rx = *(const ushort4*)(xr + rb);
      ushort4 rs = *(const ushort4*)(xs + (rb & 63));
      f32x4 v = acc[mt][nt];
      ACC[(nh * 128 + rb + 0) * 128 + co] = f2b(v[0] + b2f(rx.x) + b2f(rs.x));
      ACC[(nh * 128 + rb + 1) * 128 + co] = f2b(v[1] + b2f(rx.y) + b2f(rs.y));
      ACC[(nh * 128 + rb + 2) * 128 + co] = f2b(v[2] + b2f(rx.z) + b2f(rs.z));
      ACC[(nh * 128 + rb + 3) * 128 + co] = f2b(v[3] + b2f(rx.w) + b2f(rs.w));
    }
  }
}

// ------------- local FU forward DFT (W=64), all-LDS -------------------------------
__global__ __launch_bounds__(256) void k_dftl(const unsigned short* __restrict__ DFTm,
                                              const unsigned short* __restrict__ X1c,
                                              unsigned short* __restrict__ FFl) {
  __shared__ __align__(16) unsigned short A_s[80 * 64];    // 10 KB
  __shared__ __align__(16) unsigned short B_s[128 * 64];   // 16 KB
  int t = threadIdx.x; int wid = t >> 6, l = t & 63;
  int lr = l & 15, lg = l >> 4;
  int b = blockIdx.x; int n = b >> 6, h2 = b & 63;
  int n0 = wid * 32;
  int wb_ = (t >> 6) * 1024;
  const char* Ab = (const char*)DFTm;
  #pragma unroll
  for (int i = 0; i < 3; i++) {
    if (i * 4096 + t * 16 < 10240)
      gl16(Ab + i * 4096 + t * 16, (char*)A_s + i * 4096 + wb_);
  }
  {
    int c2q = t >> 3, q = t & 7;
    #pragma unroll
    for (int i = 0; i < 4; i++) {
      int c2 = i * 32 + c2q;
      int c0 = c2 & 31, hb = (c2 >> 5) & 1, wbq = (c2 >> 6) & 1;
      const char* src = (const char*)X1c +
          ((size_t)(n * 128 + hb * 64 + h2) * 16384 + (size_t)c0 * 128 + wbq * 64 + q * 8) * 2;
      gl16(src, (char*)B_s + i * 4096 + wb_);
    }
  }
  __syncthreads();
  f32x4 acc[5][2];
  #pragma unroll
  for (int mt = 0; mt < 5; mt++) { acc[mt][0] = (f32x4){0,0,0,0}; acc[mt][1] = (f32x4){0,0,0,0}; }
  for (int kk = 0; kk < 64; kk += 32) {
    short8 af[5], bf[2];
    #pragma unroll
    for (int mt = 0; mt < 5; mt++)
      af[mt] = *(const short8*)((const char*)A_s + (size_t)(16 * mt + lr) * 128 + kk * 2 + lg * 16);
    #pragma unroll
    for (int nt = 0; nt < 2; nt++)
      bf[nt] = *(const short8*)((const char*)B_s + (size_t)(n0 + 16 * nt + lr) * 128 + kk * 2 + lg * 16);
    #pragma unroll
    for (int mt = 0; mt < 5; mt++)
      #pragma unroll
      for (int nt = 0; nt < 2; nt++)
        acc[mt][nt] = __builtin_amdgcn_mfma_f32_16x16x32_bf16(af[mt], bf[nt], acc[mt][nt], 0, 0, 0);
  }
  #pragma unroll
  for (int nt = 0; nt < 2; nt++) {
    int c2 = n0 + 16 * nt + lr;
    #pragma unroll
    for (int mt = 0; mt < 5; mt++) {
      int rb = 16 * mt + lg * 4;
      int wf0 = rb >> 1;
      f32x4 v = acc[mt][nt];
      if (wf0 < 33) {
        unsigned pk = (unsigned)f2b(v[0]) | ((unsigned)f2b(v[1]) << 16);
        *(unsigned*)(FFl + ((size_t)((n * 64 + h2) * 33 + wf0)) * 256 + 2 * c2) = pk;
      }
      if (wf0 + 1 < 33) {
        unsigned pk = (unsigned)f2b(v[2]) | ((unsigned)f2b(v[3]) << 16);
        *(unsigned*)(FFl + ((size_t)((n * 64 + h2) * 33 + wf0 + 1)) * 256 + 2 * c2) = pk;
      }
    }
  }
}

// ------------- local FU inverse DFT (W=64) -> XSO, all-LDS ------------------------
__global__ __launch_bounds__(256) void k_idftl(const unsigned short* __restrict__ IDFTm,
                                               const unsigned short* __restrict__ Ycl,
                                               unsigned short* __restrict__ XSO) {
  __shared__ __align__(16) unsigned short A_s[64 * 96];    // 12 KB
  __shared__ __align__(16) unsigned short B_s[128 * 96];   // 24 KB
  int t = threadIdx.x; int wid = t >> 6, l = t & 63;
  int lr = l & 15, lg = l >> 4;
  int b = blockIdx.x; int n = b >> 6, h2 = b & 63;
  int n0 = wid * 32;
  int wb_ = (t >> 6) * 1024;
  const char* Ab = (const char*)IDFTm;
  const char* Bb = (const char*)Ycl + (size_t)(n * 64 + h2) * 128 * 192;
  #pragma unroll
  for (int i = 0; i < 3; i++) gl16(Ab + i * 4096 + t * 16, (char*)A_s + i * 4096 + wb_);
  #pragma unroll
  for (int i = 0; i < 6; i++) gl16(Bb + i * 4096 + t * 16, (char*)B_s + i * 4096 + wb_);
  __syncthreads();
  f32x4 acc[4][2];
  #pragma unroll
  for (int mt = 0; mt < 4; mt++) { acc[mt][0] = (f32x4){0,0,0,0}; acc[mt][1] = (f32x4){0,0,0,0}; }
  for (int kk = 0; kk < 96; kk += 32) {
    short8 af[4], bf[2];
    #pragma unroll
    for (int mt = 0; mt < 4; mt++)
      af[mt] = *(const short8*)((const char*)A_s + (size_t)(16 * mt + lr) * 192 + kk * 2 + lg * 16);
    #pragma unroll
    for (int nt = 0; nt < 2; nt++)
      bf[nt] = *(const short8*)((const char*)B_s + (size_t)(n0 + 16 * nt + lr) * 192 + kk * 2 + lg * 16);
    #pragma unroll
    for (int mt = 0; mt < 4; mt++)
      #pragma unroll
      for (int nt = 0; nt < 2; nt++)
        acc[mt][nt] = __builtin_amdgcn_mfma_f32_16x16x32_bf16(af[mt], bf[nt], acc[mt][nt], 0, 0, 0);
  }
  #pragma unroll
  for (int nt = 0; nt < 2; nt++) {
    int co = n0 + 16 * nt + lr;
    #pragma unroll
    for (int mt = 0; mt < 4; mt++) {
      int rb = 16 * mt + lg * 4;
      f32x4 v = acc[mt][nt];
      ushort4 o;
      o.x = f2b(v[0]); o.y = f2b(v[1]); o.z = f2b(v[2]); o.w = f2b(v[3]);
      *(ushort4*)(XSO + (((size_t)n * 128 + co) * 64 + h2) * 64 + rb) = o;
    }
  }
}

// ------------- conv2: ACC[(nhw)][128] -> out[(nhw)][256] f32 ----------------------
__global__ __launch_bounds__(512) void k_conv2(const unsigned short* __restrict__ A,
                                               const unsigned short* __restrict__ B,
                                               float* __restrict__ out) {
  __shared__ __align__(16) unsigned short A_s[256 * 128];  // 64 KB
  __shared__ __align__(16) unsigned short B_s[128 * 32];   // 8 KB
  int t = threadIdx.x; int wid = t >> 6, l = t & 63;
  int wm = wid >> 1, wn = wid & 1;
  int m0 = wm * 64; size_t col0 = (size_t)blockIdx.x * 128 + wn * 64;
  int lr = l & 15, lg = l >> 4;
  int wb_ = (t >> 6) * 1024;
  const char* Ab = (const char*)A;
  const char* Bb = (const char*)B + (size_t)blockIdx.x * 128 * 256;
  #pragma unroll
  for (int i = 0; i < 8; i++) gl16(Ab + i * 8192 + t * 16, (char*)A_s + i * 8192 + wb_);
  f32x4 acc[4][4];
  #pragma unroll
  for (int mt = 0; mt < 4; mt++)
    #pragma unroll
    for (int nt = 0; nt < 4; nt++) acc[mt][nt] = (f32x4){0.f, 0.f, 0.f, 0.f};
  int c4 = t >> 2, q4 = t & 3;
  for (int kk = 0; kk < 128; kk += 32) {
    if (kk) __syncthreads();
    gl16(Bb + (size_t)c4 * 256 + kk * 2 + q4 * 16, (char*)B_s + wb_);
    __syncthreads();
    short8 af[4], bf[4];
    #pragma unroll
    for (int mt = 0; mt < 4; mt++)
      af[mt] = *(const short8*)((const char*)A_s + (size_t)(m0 + 16 * mt + lr) * 256 + kk * 2 + lg * 16);
    #pragma unroll
    for (int nt = 0; nt < 4; nt++)
      bf[nt] = *(const short8*)((const char*)B_s + (size_t)(wn * 64 + 16 * nt + lr) * 64 + lg * 16);
    #pragma unroll
    for (int mt = 0; mt < 4; mt++)
      #pragma unroll
      for (int nt = 0; nt < 4; nt++)
        acc[mt][nt] = __builtin_amdgcn_mfma_f32_16x16x32_bf16(af[mt], bf[nt], acc[mt][nt], 0, 0, 0);
  }
  #pragma unroll
  for (int nt = 0; nt < 4; nt++) {
    size_t col = col0 + 16 * nt + lr;
    #pragma unroll
    for (int mt = 0; mt < 4; mt++) {
      int rb = m0 + 16 * mt + lg * 4;
      f32x4 v = acc[mt][nt];
      float4 o; o.x = v[0]; o.y = v[1]; o.z = v[2]; o.w = v[3];
      *(float4*)(out + col * 256 + rb) = o;
    }
  }
}

extern "C" void kernel_launch(void* const* d_in, const int* in_sizes, int n_in,
                              void* d_out, int out_size, void* d_ws, size_t ws_size,
                              hipStream_t stream) {
  const float* x     = (const float*)d_in[0];
  const float* w1    = (const float*)d_in[1];
  const float* g1    = (const float*)d_in[2];
  const float* b1    = (const float*)d_in[3];
  const float* m1    = (const float*)d_in[4];
  const float* v1    = (const float*)d_in[5];
  const float* fu_w  = (const float*)d_in[6];
  const float* fu_g  = (const float*)d_in[7];
  const float* fu_b  = (const float*)d_in[8];
  const float* fu_m  = (const float*)d_in[9];
  const float* fu_v  = (const float*)d_in[10];
  const float* lfu_w = (const float*)d_in[11];
  const float* lfu_g = (const float*)d_in[12];
  const float* lfu_b = (const float*)d_in[13];
  const float* lfu_m = (const float*)d_in[14];
  const float* lfu_v = (const float*)d_in[15];
  const float* w2    = (const float*)d_in[16];
  float* out = (float*)d_out;

  char* p = (char*)d_ws;
  unsigned short* X1c = (unsigned short*)p; p += 33554432;         // [nh][c][w] bf16
  unsigned short* XSO = (unsigned short*)p; p += 8388608;          // [n][c][h2][w2] bf16
  char* bufC = p; p += 41943040;                                   // FFl, then Yc
  char* bufD = p; p += 34078720;                                   // Ycl, then FF, then ACC
  unsigned short* FFl = (unsigned short*)bufC;                     // 16896*256
  unsigned short* Yc  = (unsigned short*)bufC;                     // 1024*128*160
  unsigned short* Ycl = (unsigned short*)bufD;                     // 512*128*96
  unsigned short* FF  = (unsigned short*)bufD;                     // 66560*256
  unsigned short* ACC = (unsigned short*)bufD;                     // 131072*128
  unsigned short* w1b   = (unsigned short*)p; p += 65536;
  unsigned short* fuwb  = (unsigned short*)p; p += 131072;
  unsigned short* lfuwb = (unsigned short*)p; p += 131072;
  unsigned short* w2b   = (unsigned short*)p; p += 65536;
  unsigned short* DFTf  = (unsigned short*)p; p += 36864;
  unsigned short* IDFTf = (unsigned short*)p; p += 40960;
  unsigned short* DFTl  = (unsigned short*)p; p += 10240;
  unsigned short* IDFTl = (unsigned short*)p; p += 12288;
  float* sc1 = (float*)p; p += 512;
  float* sh1 = (float*)p; p += 512;
  float* scF = (float*)p; p += 1024;
  float* shF = (float*)p; p += 1024;
  float* scL = (float*)p; p += 1024;
  float* shL = (float*)p; p += 1024;

  k_wt<<<dim3(256), dim3(256), 0, stream>>>(w1, fu_w, lfu_w, w2, g1, b1, m1, v1,
                                            fu_g, fu_b, fu_m, fu_v, lfu_g, lfu_b, lfu_m, lfu_v,
                                            w1b, fuwb, lfuwb, w2b, DFTf, IDFTf, DFTl, IDFTl,
                                            sc1, sh1, scF, shF, scL, shL);
  k_conv1<<<dim3(1024), dim3(256), 0, stream>>>(w1b, x, X1c, sc1, sh1);
  k_dftl<<<dim3(512), dim3(256), 0, stream>>>(DFTl, X1c, FFl);
  k_conv_perm<33, 96><<<dim3(132), dim3(512), 0, stream>>>(lfuwb, FFl, Ycl, scL, shL);
  k_idftl<<<dim3(512), dim3(256), 0, stream>>>(IDFTl, Ycl, XSO);
  k_dftf<<<dim3(1024), dim3(256), 0, stream>>>(DFTf, X1c, FF);
  k_conv_perm<65, 160><<<dim3(520), dim3(512), 0, stream>>>(fuwb, FF, Yc, scF, shF);
  k_idftf<<<dim3(1024), dim3(256), 0, stream>>>(IDFTf, Yc, X1c, XSO, ACC);
  k_conv2<<<dim3(1024), dim3(512), 0, stream>>>(w2b, ACC, out);
}

// Round 5
// 174.422 us; speedup vs baseline: 5.3138x; 1.2425x over previous
//
#include <hip/hip_runtime.h>
#include <math.h>

typedef __attribute__((ext_vector_type(8))) short short8;
typedef __attribute__((ext_vector_type(4))) float f32x4;

#define SW7b(r) (((r) & 7) << 4)
#define SW3b(r) (((r) & 3) << 4)

static __device__ __forceinline__ unsigned short f2b(float f){
  unsigned u = __float_as_uint(f);
  u = (u + 0x7FFFu + ((u >> 16) & 1u)) >> 16;
  return (unsigned short)u;
}
static __device__ __forceinline__ float b2f(unsigned short u){
  return __uint_as_float(((unsigned)u) << 16);
}
static __device__ __forceinline__ void gl16(const void* g, void* l) {
  __builtin_amdgcn_global_load_lds(
      (const __attribute__((address_space(1))) void*)g,
      (__attribute__((address_space(3))) void*)l, 16, 0, 0);
}

// ---------------- weight/matrix prep: everything pre-swizzled ---------------------
__global__ void k_wt(const float* __restrict__ w1, const float* __restrict__ fu_w,
                     const float* __restrict__ lfu_w, const float* __restrict__ w2,
                     const float* __restrict__ g1, const float* __restrict__ b1,
                     const float* __restrict__ m1, const float* __restrict__ v1,
                     const float* __restrict__ fg, const float* __restrict__ fb,
                     const float* __restrict__ fm, const float* __restrict__ fv,
                     const float* __restrict__ lg_, const float* __restrict__ lb_,
                     const float* __restrict__ lm_, const float* __restrict__ lv_,
                     unsigned short* __restrict__ w1b, unsigned short* __restrict__ fuwb,
                     unsigned short* __restrict__ lfuwb, unsigned short* __restrict__ w2b,
                     unsigned short* __restrict__ DFTf, unsigned short* __restrict__ IDFTf,
                     unsigned short* __restrict__ DFTl, unsigned short* __restrict__ IDFTl,
                     float* __restrict__ sc1, float* __restrict__ sh1,
                     float* __restrict__ scF, float* __restrict__ shF,
                     float* __restrict__ scL, float* __restrict__ shL) {
  int t = blockIdx.x * 256 + threadIdx.x;
  const float TPI = 6.283185307179586f;
  if (t < 32768) {
    { int co = t >> 8, k = t & 255; w1b[co * 256 + (k ^ ((co & 7) << 3))] = f2b(w1[t]); }
    { int co = t >> 7, k = t & 127; w2b[co * 128 + (k ^ ((co & 7) << 3))] = f2b(w2[t]); }
  }
  if (t < 65536) {
    int co = t >> 8, k = t & 255;
    int ks = k ^ ((co & 7) << 3);
    fuwb[co * 256 + ks] = f2b(fu_w[t]);
    lfuwb[co * 256 + ks] = f2b(lfu_w[t]);
  }
  if (t < 18432) {                      // DFTf[144][128], rows 256B, key m&7
    int m = t >> 7, w = t & 127; float v = 0.f;
    if (m < 130) {
      int wf = m >> 1; int ph = (wf * w) & 127;
      float ang = TPI * (float)ph / 128.f;
      v = ((m & 1) ? -sinf(ang) : cosf(ang)) * 0.08838834764831845f;
    }
    DFTf[m * 128 + (w ^ ((m & 7) << 3))] = f2b(v);
  }
  if (t < 20480) {                      // IDFTf[128][160], rows 320B, key m&3
    int m = t / 160, k2 = t % 160; float v = 0.f;
    if (k2 < 130) {
      int wf = k2 >> 1; float a = (wf == 0 || wf == 64) ? 1.f : 2.f;
      int ph = (wf * m) & 127;
      float ang = TPI * (float)ph / 128.f;
      v = ((k2 & 1) ? -a * sinf(ang) : a * cosf(ang)) * 0.08838834764831845f;
    }
    IDFTf[m * 160 + (k2 ^ ((m & 3) << 3))] = f2b(v);
  }
  if (t < 5120) {                       // DFTl[80][64], rows 128B, key m&7
    int m = t >> 6, w = t & 63; float v = 0.f;
    if (m < 66) {
      int wf = m >> 1; int ph = (wf * w) & 63;
      float ang = TPI * (float)ph / 64.f;
      v = ((m & 1) ? -sinf(ang) : cosf(ang)) * 0.125f;
    }
    DFTl[m * 64 + (w ^ ((m & 7) << 3))] = f2b(v);
  }
  if (t < 6144) {                       // IDFTl[64][96], rows 192B, key m&3
    int m = t / 96, k2 = t % 96; float v = 0.f;
    if (k2 < 66) {
      int wf = k2 >> 1; float a = (wf == 0 || wf == 32) ? 1.f : 2.f;
      int ph = (wf * m) & 63;
      float ang = TPI * (float)ph / 64.f;
      v = ((k2 & 1) ? -a * sinf(ang) : a * cosf(ang)) * 0.125f;
    }
    IDFTl[m * 96 + (k2 ^ ((m & 3) << 3))] = f2b(v);
  }
  if (t < 128) { float s = g1[t] * rsqrtf(v1[t] + 1e-3f); sc1[t] = s; sh1[t] = b1[t] - m1[t] * s; }
  if (t < 256) { float s = fg[t] * rsqrtf(fv[t] + 1e-3f); scF[t] = s; shF[t] = fb[t] - fm[t] * s; }
  if (t < 256) { float s = lg_[t] * rsqrtf(lv_[t] + 1e-3f); scL[t] = s; shL[t] = lb_[t] - lm_[t] * s; }
}

// ------------- conv1: x NHWC f32 (K=256) -> X1c[nh][c][w] bf16 SWIZZLED -----------
__global__ __launch_bounds__(256) void k_conv1(const unsigned short* __restrict__ A,
                                               const float* __restrict__ x,
                                               unsigned short* __restrict__ X1c,
                                               const float* __restrict__ scp,
                                               const float* __restrict__ shp) {
  __shared__ __align__(16) char A_s[128 * 512];  // 64 KB, rows 512B, key r&7 (prestored)
  __shared__ __align__(16) char B_s[128 * 128];  // 16 KB f32 x-tile, rows 128B, key r&7
  int t = threadIdx.x; int wid = t >> 6, l = t & 63;
  int wm = wid >> 1, wn = wid & 1;
  int m0 = wm * 64; int lr = l & 15, lg = l >> 4;
  size_t nh = blockIdx.x;
  const char* Ab = (const char*)A;
  const char* xrow = (const char*)(x + nh * 128 * 256);
  #pragma unroll
  for (int i = 0; i < 16; i++) { int g = i * 256 + t; gl16(Ab + g * 16, A_s + g * 16); }
  f32x4 acc[4][4];
  #pragma unroll
  for (int mt = 0; mt < 4; mt++)
    #pragma unroll
    for (int nt = 0; nt < 4; nt++) acc[mt][nt] = (f32x4){0.f, 0.f, 0.f, 0.f};
  for (int kk = 0; kk < 256; kk += 32) {
    #pragma unroll
    for (int i = 0; i < 4; i++) {
      int g = i * 256 + t; int w = g >> 3, o = g & 7;
      gl16(xrow + (size_t)w * 1024 + kk * 4 + ((o * 16) ^ SW7b(w)), B_s + g * 16);
    }
    __syncthreads();
    short8 af[4], bf[4];
    #pragma unroll
    for (int mt = 0; mt < 4; mt++) {
      int m = m0 + 16 * mt + lr;
      af[mt] = *(const short8*)(A_s + m * 512 + ((kk * 2 + lg * 16) ^ SW7b(m)));
    }
    #pragma unroll
    for (int nt = 0; nt < 4; nt++) {
      int w = wn * 64 + 16 * nt + lr;
      float4 f0 = *(const float4*)(B_s + w * 128 + ((lg * 32) ^ SW7b(w)));
      float4 f1 = *(const float4*)(B_s + w * 128 + ((lg * 32 + 16) ^ SW7b(w)));
      short8 bb;
      bb[0] = (short)f2b(f0.x); bb[1] = (short)f2b(f0.y);
      bb[2] = (short)f2b(f0.z); bb[3] = (short)f2b(f0.w);
      bb[4] = (short)f2b(f1.x); bb[5] = (short)f2b(f1.y);
      bb[6] = (short)f2b(f1.z); bb[7] = (short)f2b(f1.w);
      bf[nt] = bb;
    }
    #pragma unroll
    for (int mt = 0; mt < 4; mt++)
      #pragma unroll
      for (int nt = 0; nt < 4; nt++)
        acc[mt][nt] = __builtin_amdgcn_mfma_f32_16x16x32_bf16(af[mt], bf[nt], acc[mt][nt], 0, 0, 0);
    __syncthreads();
  }
  char* xout = (char*)X1c + nh * 32768;
  #pragma unroll
  for (int nt = 0; nt < 4; nt++) {
    int w = wn * 64 + 16 * nt + lr;
    #pragma unroll
    for (int mt = 0; mt < 4; mt++) {
      int rb = m0 + 16 * mt + lg * 4;
      float4 s4 = *(const float4*)&scp[rb];
      float4 h4 = *(const float4*)&shp[rb];
      f32x4 v = acc[mt][nt];
      *(unsigned short*)(xout + (rb + 0) * 256 + ((w * 2) ^ SW7b(rb + 0))) = f2b(fmaxf(v[0] * s4.x + h4.x, 0.f));
      *(unsigned short*)(xout + (rb + 1) * 256 + ((w * 2) ^ SW7b(rb + 1))) = f2b(fmaxf(v[1] * s4.y + h4.y, 0.f));
      *(unsigned short*)(xout + (rb + 2) * 256 + ((w * 2) ^ SW7b(rb + 2))) = f2b(fmaxf(v[2] * s4.z + h4.z, 0.f));
      *(unsigned short*)(xout + (rb + 3) * 256 + ((w * 2) ^ SW7b(rb + 3))) = f2b(fmaxf(v[3] * s4.w + h4.w, 0.f));
    }
  }
}

// ------------- fused local Fourier unit: X1c quadrants -> XSO ---------------------
__global__ __launch_bounds__(256) void k_lfu(const unsigned short* __restrict__ DFTm,
                                             const unsigned short* __restrict__ lfuw,
                                             const unsigned short* __restrict__ IDFTm,
                                             const unsigned short* __restrict__ X1c,
                                             const float* __restrict__ scp,
                                             const float* __restrict__ shp,
                                             unsigned short* __restrict__ XSO) {
  __shared__ __align__(16) char SH[81920];
  char* M   = SH;            // 16KB: DFTl 10 / lfuw chunk 16 / IDFTl 12
  char* Xs  = SH + 16384;    // 16KB [128 c2][128B] (swizzled content, key c2&7)
  char* FFl = SH + 32768;    // 24KB [48 wf][512B] key wf&7
  char* Yl  = SH + 57344;    // 24KB [128 cc][192B] key cc&3
  int t = threadIdx.x, wid = t >> 6, l = t & 63, lr = l & 15, lg = l >> 4;
  int b = blockIdx.x; int n = b >> 6, h2 = b & 63;
  // P0: stage DFTl + Xs, zero FFl pad rows
  {
    const char* src = (const char*)DFTm;
    #pragma unroll
    for (int i = 0; i < 3; i++) { int g = i * 256 + t; if (g < 640) gl16(src + g * 16, M + g * 16); }
    #pragma unroll
    for (int i = 0; i < 4; i++) {
      int g = i * 256 + t; int c2 = g >> 3, o = g & 7;
      int c0 = c2 & 31, hb = (c2 >> 5) & 1, wbq = (c2 >> 6) & 1;
      const char* s = (const char*)X1c +
          ((size_t)(n * 128 + hb * 64 + h2) * 128 + c0) * 256 + wbq * 128 + o * 16;
      gl16(s, Xs + g * 16);
    }
    #pragma unroll
    for (int i = 0; i < 8; i++) {
      int u = i * 256 + t;
      if (u < 1920) *(unsigned*)(FFl + 33 * 512 + u * 4) = 0u;
    }
  }
  __syncthreads();
  // P1: FFl = DFTl . Xs
  {
    f32x4 acc[5][2];
    #pragma unroll
    for (int mt = 0; mt < 5; mt++) { acc[mt][0] = (f32x4){0,0,0,0}; acc[mt][1] = (f32x4){0,0,0,0}; }
    for (int kk = 0; kk < 64; kk += 32) {
      int kb = kk * 2 + lg * 16;
      short8 bf[2];
      #pragma unroll
      for (int nt = 0; nt < 2; nt++) {
        int c2 = wid * 32 + 16 * nt + lr;
        bf[nt] = *(const short8*)(Xs + c2 * 128 + (kb ^ SW7b(c2)));
      }
      #pragma unroll
      for (int mt = 0; mt < 5; mt++) {
        int m = 16 * mt + lr;
        short8 af = *(const short8*)(M + m * 128 + (kb ^ SW7b(m)));
        #pragma unroll
        for (int nt = 0; nt < 2; nt++)
          acc[mt][nt] = __builtin_amdgcn_mfma_f32_16x16x32_bf16(af, bf[nt], acc[mt][nt], 0, 0, 0);
      }
    }
    #pragma unroll
    for (int nt = 0; nt < 2; nt++) {
      int c2 = wid * 32 + 16 * nt + lr;
      #pragma unroll
      for (int mt = 0; mt < 5; mt++) {
        int rb = 16 * mt + lg * 4;
        int wf0 = rb >> 1;
        f32x4 v = acc[mt][nt];
        if (wf0 < 33) {
          unsigned pk = (unsigned)f2b(v[0]) | ((unsigned)f2b(v[1]) << 16);
          *(unsigned*)(FFl + wf0 * 512 + ((4 * c2) ^ SW7b(wf0))) = pk;
        }
        if (wf0 + 1 < 33) {
          unsigned pk = (unsigned)f2b(v[2]) | ((unsigned)f2b(v[3]) << 16);
          *(unsigned*)(FFl + (wf0 + 1) * 512 + ((4 * c2) ^ SW7b(wf0 + 1))) = pk;
        }
      }
    }
  }
  __syncthreads();
  // P2: Yl = ReLU(BN(lfuw . FFl)), 8 chunks of 32 co
  int wm2 = wid >> 1, wn2 = wid & 1;
  for (int ch = 0; ch < 8; ch++) {
    {
      const char* src = (const char*)lfuw + (size_t)ch * 16384;
      #pragma unroll
      for (int i = 0; i < 4; i++) { int g = i * 256 + t; gl16(src + g * 16, M + g * 16); }
    }
    __syncthreads();
    int NT = wn2 ? 1 : 2;
    f32x4 acc[2];
    acc[0] = (f32x4){0,0,0,0}; acc[1] = (f32x4){0,0,0,0};
    int lm = wm2 * 16 + lr;
    for (int kk = 0; kk < 256; kk += 32) {
      int kb = kk * 2 + lg * 16;
      short8 af = *(const short8*)(M + lm * 512 + (kb ^ SW7b(lm)));
      #pragma unroll
      for (int j = 0; j < 2; j++) {
        if (j < NT) {
          int wf = wn2 * 32 + 16 * j + lr;
          short8 bf = *(const short8*)(FFl + wf * 512 + (kb ^ SW7b(wf)));
          acc[j] = __builtin_amdgcn_mfma_f32_16x16x32_bf16(af, bf, acc[j], 0, 0, 0);
        }
      }
    }
    int co = ch * 32 + wm2 * 16 + lg * 4;
    float4 s4 = *(const float4*)&scp[co];
    float4 h4 = *(const float4*)&shp[co];
    int cc0 = co >> 1;
    #pragma unroll
    for (int j = 0; j < 2; j++) {
      if (j < NT) {
        int wf = wn2 * 32 + 16 * j + lr;
        f32x4 v = acc[j];
        float v0 = fmaxf(v[0] * s4.x + h4.x, 0.f);
        float v1 = fmaxf(v[1] * s4.y + h4.y, 0.f);
        float v2 = fmaxf(v[2] * s4.z + h4.z, 0.f);
        float v3 = fmaxf(v[3] * s4.w + h4.w, 0.f);
        unsigned p0 = (unsigned)f2b(v0) | ((unsigned)f2b(v1) << 16);
        unsigned p1 = (unsigned)f2b(v2) | ((unsigned)f2b(v3) << 16);
        *(unsigned*)(Yl + (cc0 + 0) * 192 + ((4 * wf) ^ SW3b(cc0 + 0))) = p0;
        *(unsigned*)(Yl + (cc0 + 1) * 192 + ((4 * wf) ^ SW3b(cc0 + 1))) = p1;
      }
    }
    __syncthreads();
  }
  // P3: XSO = IDFTl . Yl
  {
    const char* src = (const char*)IDFTm;
    #pragma unroll
    for (int i = 0; i < 3; i++) { int g = i * 256 + t; gl16(src + g * 16, M + g * 16); }
  }
  __syncthreads();
  {
    f32x4 acc[8];
    #pragma unroll
    for (int nt = 0; nt < 8; nt++) acc[nt] = (f32x4){0,0,0,0};
    int w = wid * 16 + lr;
    for (int kk = 0; kk < 96; kk += 32) {
      int kb = kk * 2 + lg * 16;
      short8 af = *(const short8*)(M + w * 192 + (kb ^ SW3b(w)));
      #pragma unroll
      for (int nt = 0; nt < 8; nt++) {
        int cc = 16 * nt + lr;
        short8 bf = *(const short8*)(Yl + cc * 192 + (kb ^ SW3b(cc)));
        acc[nt] = __builtin_amdgcn_mfma_f32_16x16x32_bf16(af, bf, acc[nt], 0, 0, 0);
      }
    }
    int w0 = wid * 16 + lg * 4;
    #pragma unroll
    for (int nt = 0; nt < 8; nt++) {
      int cc = 16 * nt + lr;
      f32x4 v = acc[nt];
      ushort4 o;
      o.x = f2b(v[0]); o.y = f2b(v[1]); o.z = f2b(v[2]); o.w = f2b(v[3]);
      *(ushort4*)(XSO + (((size_t)n * 128 + cc) * 64 + h2) * 64 + w0) = o;
    }
  }
}

// ------------- fused Fourier unit + residual + conv2, per (n,h) -------------------
__global__ __launch_bounds__(512) void k_fu(const unsigned short* __restrict__ DFTm,
                                            const unsigned short* __restrict__ fuw,
                                            const unsigned short* __restrict__ IDFTm,
                                            const unsigned short* __restrict__ w2m,
                                            const unsigned short* __restrict__ X1c,
                                            const unsigned short* __restrict__ XSO,
                                            const float* __restrict__ scF,
                                            const float* __restrict__ shF,
                                            float* __restrict__ out) {
  __shared__ __align__(16) char SH[155648];
  char* M  = SH;             // 40KB: DFTf 36 / fuw chunk 32 / IDFTf 40 / w2 chunk 32
  char* Xs = SH + 40960;     // 32KB [128 c][256B] key c&7 (content pre-swizzled)
  char* FF = SH + 73728;     // 40KB [80 wf][512B] key wf&7; later ACC [128 w][256B] key w&7
  char* Yb = SH + 114688;    // 40KB [128 cc][320B] key cc&3
  int t = threadIdx.x, wid = t >> 6, l = t & 63, lr = l & 15, lg = l >> 4;
  size_t nh = blockIdx.x;
  int n = (int)(nh >> 7), h = (int)(nh & 127);
  // P0 staging: DFTf -> M, X row -> Xs, zero FF rows 65..79
  {
    const char* src = (const char*)DFTm;
    #pragma unroll
    for (int i = 0; i < 5; i++) { int g = i * 512 + t; if (g < 2304) gl16(src + g * 16, M + g * 16); }
    const char* xsrc = (const char*)X1c + nh * 32768;
    #pragma unroll
    for (int i = 0; i < 4; i++) { int g = i * 512 + t; gl16(xsrc + g * 16, Xs + g * 16); }
    #pragma unroll
    for (int i = 0; i < 4; i++) {
      int u = i * 512 + t;
      if (u < 1920) *(unsigned*)(FF + 65 * 512 + u * 4) = 0u;
    }
  }
  __syncthreads();
  // P1: FF[wf][2c+ri] = DFTf . X
  {
    f32x4 acc[9];
    #pragma unroll
    for (int mt = 0; mt < 9; mt++) acc[mt] = (f32x4){0,0,0,0};
    int c = wid * 16 + lr;
    for (int kk = 0; kk < 128; kk += 32) {
      int kb = kk * 2 + lg * 16;
      short8 bf = *(const short8*)(Xs + c * 256 + (kb ^ SW7b(c)));
      #pragma unroll
      for (int mt = 0; mt < 9; mt++) {
        int m = 16 * mt + lr;
        short8 af = *(const short8*)(M + m * 256 + (kb ^ SW7b(m)));
        acc[mt] = __builtin_amdgcn_mfma_f32_16x16x32_bf16(af, bf, acc[mt], 0, 0, 0);
      }
    }
    #pragma unroll
    for (int mt = 0; mt < 9; mt++) {
      int rb = 16 * mt + lg * 4;
      int wf0 = rb >> 1;
      f32x4 v = acc[mt];
      if (wf0 < 65) {
        unsigned pk = (unsigned)f2b(v[0]) | ((unsigned)f2b(v[1]) << 16);
        *(unsigned*)(FF + wf0 * 512 + ((4 * c) ^ SW7b(wf0))) = pk;
      }
      if (wf0 + 1 < 65) {
        unsigned pk = (unsigned)f2b(v[2]) | ((unsigned)f2b(v[3]) << 16);
        *(unsigned*)(FF + (wf0 + 1) * 512 + ((4 * c) ^ SW7b(wf0 + 1))) = pk;
      }
    }
  }
  __syncthreads();
  // P2: Y[cc][2wf+ri] = ReLU(BN(fuw . FF)), 4 chunks of 64 co
  int wm2 = wid >> 1, wn2 = wid & 1;
  for (int ch = 0; ch < 4; ch++) {
    {
      const char* src = (const char*)fuw + (size_t)ch * 32768;
      #pragma unroll
      for (int i = 0; i < 4; i++) { int g = i * 512 + t; gl16(src + g * 16, M + g * 16); }
    }
    __syncthreads();
    int NT = wn2 ? 2 : 3;
    f32x4 acc[3];
    acc[0] = (f32x4){0,0,0,0}; acc[1] = (f32x4){0,0,0,0}; acc[2] = (f32x4){0,0,0,0};
    int lm = wm2 * 16 + lr;
    for (int kk = 0; kk < 256; kk += 32) {
      int kb = kk * 2 + lg * 16;
      short8 af = *(const short8*)(M + lm * 512 + (kb ^ SW7b(lm)));
      #pragma unroll
      for (int j = 0; j < 3; j++) {
        if (j < NT) {
          int wf = wn2 * 48 + 16 * j + lr;
          short8 bf = *(const short8*)(FF + wf * 512 + (kb ^ SW7b(wf)));
          acc[j] = __builtin_amdgcn_mfma_f32_16x16x32_bf16(af, bf, acc[j], 0, 0, 0);
        }
      }
    }
    int co = ch * 64 + wm2 * 16 + lg * 4;
    float4 s4 = *(const float4*)&scF[co];
    float4 h4 = *(const float4*)&shF[co];
    int cc0 = co >> 1;
    #pragma unroll
    for (int j = 0; j < 3; j++) {
      if (j < NT) {
        int wf = wn2 * 48 + 16 * j + lr;
        f32x4 v = acc[j];
        float v0 = fmaxf(v[0] * s4.x + h4.x, 0.f);
        float v1 = fmaxf(v[1] * s4.y + h4.y, 0.f);
        float v2 = fmaxf(v[2] * s4.z + h4.z, 0.f);
        float v3 = fmaxf(v[3] * s4.w + h4.w, 0.f);
        unsigned p0 = (unsigned)f2b(v0) | ((unsigned)f2b(v1) << 16);
        unsigned p1 = (unsigned)f2b(v2) | ((unsigned)f2b(v3) << 16);
        *(unsigned*)(Yb + (cc0 + 0) * 320 + ((4 * wf) ^ SW3b(cc0 + 0))) = p0;
        *(unsigned*)(Yb + (cc0 + 1) * 320 + ((4 * wf) ^ SW3b(cc0 + 1))) = p1;
      }
    }
    __syncthreads();
  }
  // P3: ACC[w][c] = IDFTf . Y + x1 + xs   (ACC overlays FF region)
  {
    const char* src = (const char*)IDFTm;
    #pragma unroll
    for (int i = 0; i < 5; i++) { int g = i * 512 + t; gl16(src + g * 16, M + g * 16); }
  }
  __syncthreads();
  {
    f32x4 acc[8];
    #pragma unroll
    for (int nt = 0; nt < 8; nt++) acc[nt] = (f32x4){0,0,0,0};
    int w = wid * 16 + lr;
    for (int kk = 0; kk < 160; kk += 32) {
      int kb = kk * 2 + lg * 16;
      short8 af = *(const short8*)(M + w * 320 + (kb ^ SW3b(w)));
      #pragma unroll
      for (int nt = 0; nt < 8; nt++) {
        int cc = 16 * nt + lr;
        short8 bf = *(const short8*)(Yb + cc * 320 + (kb ^ SW3b(cc)));
        acc[nt] = __builtin_amdgcn_mfma_f32_16x16x32_bf16(af, bf, acc[nt], 0, 0, 0);
      }
    }
    int w0 = wid * 16 + lg * 4;
    #pragma unroll
    for (int nt = 0; nt < 8; nt++) {
      int cc = 16 * nt + lr;
      ushort4 rx = *(const ushort4*)(Xs + cc * 256 + ((w0 * 2) ^ SW7b(cc)));
      ushort4 rs = *(const ushort4*)(XSO + (((size_t)n * 128 + cc) * 64 + (h & 63)) * 64 + (w0 & 63));
      f32x4 v = acc[nt];
      float f0 = v[0] + b2f(rx.x) + b2f(rs.x);
      float f1 = v[1] + b2f(rx.y) + b2f(rs.y);
      float f2_ = v[2] + b2f(rx.z) + b2f(rs.z);
      float f3 = v[3] + b2f(rx.w) + b2f(rs.w);
      *(unsigned short*)(FF + (w0 + 0) * 256 + ((cc * 2) ^ SW7b(w0 + 0))) = f2b(f0);
      *(unsigned short*)(FF + (w0 + 1) * 256 + ((cc * 2) ^ SW7b(w0 + 1))) = f2b(f1);
      *(unsigned short*)(FF + (w0 + 2) * 256 + ((cc * 2) ^ SW7b(w0 + 2))) = f2b(f2_);
      *(unsigned short*)(FF + (w0 + 3) * 256 + ((cc * 2) ^ SW7b(w0 + 3))) = f2b(f3);
    }
  }
  __syncthreads();
  // P4: out[(nh w)][co2] = w2 . ACC, 2 chunks of 128 co2
  int wm4 = wid >> 2, wn4 = wid & 3;
  for (int ch = 0; ch < 2; ch++) {
    {
      const char* src = (const char*)w2m + (size_t)ch * 32768;
      #pragma unroll
      for (int i = 0; i < 4; i++) { int g = i * 512 + t; gl16(src + g * 16, M + g * 16); }
    }
    __syncthreads();
    f32x4 acc[4][2];
    #pragma unroll
    for (int mt = 0; mt < 4; mt++) { acc[mt][0] = (f32x4){0,0,0,0}; acc[mt][1] = (f32x4){0,0,0,0}; }
    for (int kk = 0; kk < 128; kk += 32) {
      int kb = kk * 2 + lg * 16;
      short8 af[4], bfv[2];
      #pragma unroll
      for (int mt = 0; mt < 4; mt++) {
        int lm = wm4 * 64 + 16 * mt + lr;
        af[mt] = *(const short8*)(M + lm * 256 + (kb ^ SW7b(lm)));
      }
      #pragma unroll
      for (int nt = 0; nt < 2; nt++) {
        int w = wn4 * 32 + 16 * nt + lr;
        bfv[nt] = *(const short8*)(FF + w * 256 + (kb ^ SW7b(w)));
      }
      #pragma unroll
      for (int mt = 0; mt < 4; mt++)
        #pragma unroll
        for (int nt = 0; nt < 2; nt++)
          acc[mt][nt] = __builtin_amdgcn_mfma_f32_16x16x32_bf16(af[mt], bfv[nt], acc[mt][nt], 0, 0, 0);
    }
    #pragma unroll
    for (int nt = 0; nt < 2; nt++) {
      int w = wn4 * 32 + 16 * nt + lr;
      #pragma unroll
      for (int mt = 0; mt < 4; mt++) {
        int co2 = ch * 128 + wm4 * 64 + 16 * mt + lg * 4;
        f32x4 v = acc[mt][nt];
        float4 o; o.x = v[0]; o.y = v[1]; o.z = v[2]; o.w = v[3];
        *(float4*)(out + (nh * 128 + w) * 256 + co2) = o;
      }
    }
    __syncthreads();
  }
}

extern "C" void kernel_launch(void* const* d_in, const int* in_sizes, int n_in,
                              void* d_out, int out_size, void* d_ws, size_t ws_size,
                              hipStream_t stream) {
  const float* x     = (const float*)d_in[0];
  const float* w1    = (const float*)d_in[1];
  const float* g1    = (const float*)d_in[2];
  const float* b1    = (const float*)d_in[3];
  const float* m1    = (const float*)d_in[4];
  const float* v1    = (const float*)d_in[5];
  const float* fu_w  = (const float*)d_in[6];
  const float* fu_g  = (const float*)d_in[7];
  const float* fu_b  = (const float*)d_in[8];
  const float* fu_m  = (const float*)d_in[9];
  const float* fu_v  = (const float*)d_in[10];
  const float* lfu_w = (const float*)d_in[11];
  const float* lfu_g = (const float*)d_in[12];
  const float* lfu_b = (const float*)d_in[13];
  const float* lfu_m = (const float*)d_in[14];
  const float* lfu_v = (const float*)d_in[15];
  const float* w2    = (const float*)d_in[16];
  float* out = (float*)d_out;

  char* p = (char*)d_ws;
  unsigned short* X1c = (unsigned short*)p; p += 33554432;   // [nh][c][w] bf16, swizzled rows
  unsigned short* XSO = (unsigned short*)p; p += 8388608;    // [n][cc][h2][w2] bf16
  unsigned short* w1b   = (unsigned short*)p; p += 65536;
  unsigned short* fuwb  = (unsigned short*)p; p += 131072;
  unsigned short* lfuwb = (unsigned short*)p; p += 131072;
  unsigned short* w2b   = (unsigned short*)p; p += 65536;
  unsigned short* DFTf  = (unsigned short*)p; p += 36864;
  unsigned short* IDFTf = (unsigned short*)p; p += 40960;
  unsigned short* DFTl  = (unsigned short*)p; p += 10240;
  unsigned short* IDFTl = (unsigned short*)p; p += 12288;
  float* sc1 = (float*)p; p += 512;
  float* sh1 = (float*)p; p += 512;
  float* scF = (float*)p; p += 1024;
  float* shF = (float*)p; p += 1024;
  float* scL = (float*)p; p += 1024;
  float* shL = (float*)p; p += 1024;

  k_wt<<<dim3(256), dim3(256), 0, stream>>>(w1, fu_w, lfu_w, w2, g1, b1, m1, v1,
                                            fu_g, fu_b, fu_m, fu_v, lfu_g, lfu_b, lfu_m, lfu_v,
                                            w1b, fuwb, lfuwb, w2b, DFTf, IDFTf, DFTl, IDFTl,
                                            sc1, sh1, scF, shF, scL, shL);
  k_conv1<<<dim3(1024), dim3(256), 0, stream>>>(w1b, x, X1c, sc1, sh1);
  k_lfu<<<dim3(512), dim3(256), 0, stream>>>(DFTl, lfuwb, IDFTl, X1c, scL, shL, XSO);
  k_fu<<<dim3(1024), dim3(512), 0, stream>>>(DFTf, fuwb, IDFTf, w2b, X1c, XSO, scF, shF, out);
}